// Round 3
// baseline (532.611 us; speedup 1.0000x reference)
//
#include <hip/hip_runtime.h>
#include <stdint.h>

typedef unsigned short u16;
typedef unsigned int   u32;

#define T_LEN 4000
#define NEG_INF (-3.4028234663852886e38f)

typedef __bf16 bf16x8 __attribute__((ext_vector_type(8)));
typedef float  f32x4  __attribute__((ext_vector_type(4)));

__device__ __forceinline__ u16 f2bf(float f){
    union { float f; u32 i; } v; v.f = f;
    u32 u = v.i;
    u32 r = (u + 0x7FFFu + ((u >> 16) & 1u)) >> 16;
    return (u16)r;
}
__device__ __forceinline__ float tanh_fast(float x){
    float ax = fabsf(x);
    float a = __expf(-2.0f * ax);
    float t = (1.0f - a) / (1.0f + a);
    return copysignf(t, x);
}
__device__ __forceinline__ u32 rotl32(u32 x, int n){ return (x << n) | (x >> (32 - n)); }

// async global->LDS, 16B per lane (global_load_lds_dwordx4).
// LDS dest must be linear in lane order: base + lane*16.
__device__ __forceinline__ void gll16(const void* g, void* l){
    __builtin_amdgcn_global_load_lds(
        (__attribute__((address_space(1))) void*)g,
        (__attribute__((address_space(3))) void*)l, 16, 0, 0);
}

// jax.random.normal(jax.random.key(123), (16,4000), f32) — threefry2x32. [verified]
__device__ float jax_noise(u32 idx){
    const u32 k0 = 0u, k1 = 123u;
    const u32 k2 = k0 ^ k1 ^ 0x1BD11BDAu;
    u32 x0 = k0;
    u32 x1 = idx + k1;
#define RND(r) { x0 += x1; x1 = rotl32(x1, r); x1 ^= x0; }
    RND(13) RND(15) RND(26) RND(6)   x0 += k1; x1 += k2 + 1u;
    RND(17) RND(29) RND(16) RND(24)  x0 += k2; x1 += k0 + 2u;
    RND(13) RND(15) RND(26) RND(6)   x0 += k0; x1 += k1 + 3u;
    RND(17) RND(29) RND(16) RND(24)  x0 += k1; x1 += k2 + 4u;
    RND(13) RND(15) RND(26) RND(6)   x0 += k2; x1 += k0 + 5u;
#undef RND
    u32 bits = x0 ^ x1;
    union { u32 i; float f; } u;
    u.i = (bits >> 9) | 0x3F800000u;
    float f01 = u.f - 1.0f;
    const float minval = -0.99999994f;
    float uu = f01 * (1.0f - minval) + minval;
    uu = fmaxf(uu, minval);
    return 1.41421356f * erfinvf(uu);
}

// ---------------- merged prep: vnorm, qproj, W transpose, zeroing, key->bf16 ----------------
__global__ __launch_bounds__(512) void prep_combined(
    const float* __restrict__ v_mono, const float* __restrict__ g_mono,
    const float* __restrict__ query, const float* __restrict__ wq_mono,
    const float* __restrict__ wq_chunk,
    const float* __restrict__ wk_mono, const float* __restrict__ wk_chunk,
    const float* __restrict__ key,
    float* __restrict__ vn, float* __restrict__ qp_mono, float* __restrict__ qp_chunk,
    u16* __restrict__ Wt, u16* __restrict__ kb,
    float* __restrict__ ezero, float* __restrict__ outcv)
{
    __shared__ float shf[512];
    __shared__ u16 tile[32][33];
    const int blk = blockIdx.x;
    const int tid = threadIdx.x;
    if (blk == 0){
        float v = v_mono[tid];
        shf[tid] = v * v;
        __syncthreads();
        for (int off = 256; off >= 1; off >>= 1){
            if (tid < off) shf[tid] += shf[tid + off];
            __syncthreads();
        }
        float g = g_mono[0];
        vn[tid] = g * v / sqrtf(shf[0]);
    } else if (blk <= 32){
        int b = (blk - 1) >> 1;
        int which = (blk - 1) & 1;
        const float* W = which ? wq_chunk : wq_mono;
        float* out = which ? qp_chunk : qp_mono;
        shf[tid] = query[b * 512 + tid];
        __syncthreads();
        float acc = 0.f;
        for (int k = 0; k < 512; k++) acc += shf[k] * W[k * 512 + tid];
        out[b * 512 + tid] = acc;
    } else if (blk <= 544){
        int idx = blk - 33;                     // 0..511
        int kt = (idx & 15) * 32, nt = (idx >> 4) * 32;
        int c = tid & 31, r = tid >> 5;         // 32 cols x 16 rows
        const float* src = (nt < 512) ? wk_mono : wk_chunk;
        int nbase = (nt < 512) ? nt : nt - 512;
#pragma unroll
        for (int i = 0; i < 2; i++){
            int kk = r + i * 16;
            tile[kk][c] = f2bf(src[(size_t)(kt + kk) * 512 + nbase + c]);
        }
        __syncthreads();
#pragma unroll
        for (int i = 0; i < 2; i++){
            int nn = r + i * 16;
            Wt[(size_t)(nt + nn) * 512 + kt + c] = tile[c][nn];
        }
    } else if (blk < 608){
        int i = ((blk - 545) * 512 + tid) * 4;   // zero e_mono|e_chunk (128000 floats)
        if (i < 128000){
            float4 z = {0.f, 0.f, 0.f, 0.f};
            *reinterpret_cast<float4*>(ezero + i) = z;
        }
    } else if (blk < 612){
        int i = ((blk - 608) * 512 + tid) * 4;   // zero cv accum target (8192 floats)
        float4 z = {0.f, 0.f, 0.f, 0.f};
        *reinterpret_cast<float4*>(outcv + i) = z;
    } else {
        size_t i = ((size_t)(blk - 612) * 512 + tid) * 8;
        float4 a = *reinterpret_cast<const float4*>(key + i);
        float4 b = *reinterpret_cast<const float4*>(key + i + 4);
        uint4 pk;
        pk.x = (u32)f2bf(fmaxf(a.x, 0.f)) | ((u32)f2bf(fmaxf(a.y, 0.f)) << 16);
        pk.y = (u32)f2bf(fmaxf(a.z, 0.f)) | ((u32)f2bf(fmaxf(a.w, 0.f)) << 16);
        pk.z = (u32)f2bf(fmaxf(b.x, 0.f)) | ((u32)f2bf(fmaxf(b.y, 0.f)) << 16);
        pk.w = (u32)f2bf(fmaxf(b.z, 0.f)) | ((u32)f2bf(fmaxf(b.w, 0.f)) << 16);
        *reinterpret_cast<uint4*>(kb + i) = pk;
    }
}

// ---------------- 8-phase 256x256 GEMM + energy epilogue ----------------
// 8 waves (2M x 4N), BK=64, dbuf 128 KiB LDS. WAR-safe stage windows:
// buf0 dead P5..next-P1 (stage E+2 at P5, drain P8); buf1 dead P1..P5
// (stage O at P1, drain P4). Loads span 3 phases -> drains near-free.
// XOR swizzle both sides; setprio around MFMA; raw barriers.

__device__ __forceinline__ void stageA(const u16* __restrict__ kb, u16* SH,
                                       int g0, int kt, int h, int tid){
#pragma unroll
    for (int j = 0; j < 2; j++){
        int vid = tid + j * 512;
        int rr = vid >> 3;
        int sl = (vid & 7) ^ (rr & 7);      // inverse swizzle on global source
        gll16(kb + (size_t)(g0 + h * 128 + rr) * 512 + kt * 64 + sl * 8,
              SH + (size_t)((kt & 1) * 32768 + h * 8192 + vid * 8));
    }
}
__device__ __forceinline__ void stageB(const u16* __restrict__ Wt, u16* SH,
                                       int n0, int kt, int h, int tid){
#pragma unroll
    for (int j = 0; j < 2; j++){
        int vid = tid + j * 512;
        int rr = vid >> 3;
        int sl = (vid & 7) ^ (rr & 7);
        gll16(Wt + (size_t)(n0 + h * 128 + rr) * 512 + kt * 64 + sl * 8,
              SH + (size_t)((kt & 1) * 32768 + 16384 + h * 8192 + vid * 8));
    }
}

#define DRAIN0 asm volatile("s_waitcnt vmcnt(0)" ::: "memory")
#define NODRAIN ((void)0)
#define NOSTAGE ((void)0)

#define PHASE(BSEL, MH, NH, STAGES, DRAIN) do{                                    \
    bf16x8 af[4][2], bg[2][2];                                                    \
    _Pragma("unroll") for (int mf = 0; mf < 4; mf++)                              \
    _Pragma("unroll") for (int ks = 0; ks < 2; ks++){                             \
        int rr = wm * 128 + (MH) * 64 + mf * 16 + l15;                            \
        int sl = (ks * 4 + quad) ^ (rr & 7);                                      \
        af[mf][ks] = *reinterpret_cast<const bf16x8*>(                            \
            &SH[(BSEL) * 32768 + rr * 64 + sl * 8]);                              \
    }                                                                             \
    _Pragma("unroll") for (int nf = 0; nf < 2; nf++)                              \
    _Pragma("unroll") for (int ks = 0; ks < 2; ks++){                             \
        int rr = wn * 64 + (NH) * 32 + nf * 16 + l15;                             \
        int sl = (ks * 4 + quad) ^ (rr & 7);                                      \
        bg[nf][ks] = *reinterpret_cast<const bf16x8*>(                            \
            &SH[(BSEL) * 32768 + 16384 + rr * 64 + sl * 8]);                      \
    }                                                                             \
    STAGES;                                                                       \
    DRAIN;                                                                        \
    __builtin_amdgcn_sched_barrier(0);                                            \
    __builtin_amdgcn_s_barrier();                                                 \
    asm volatile("s_waitcnt lgkmcnt(0)" ::: "memory");                            \
    __builtin_amdgcn_sched_barrier(0);                                            \
    __builtin_amdgcn_s_setprio(1);                                                \
    _Pragma("unroll") for (int mf = 0; mf < 4; mf++)                              \
    _Pragma("unroll") for (int nf = 0; nf < 2; nf++)                              \
    _Pragma("unroll") for (int ks = 0; ks < 2; ks++)                              \
        acc[(MH) * 4 + mf][(NH) * 2 + nf] =                                       \
            __builtin_amdgcn_mfma_f32_16x16x32_bf16(                              \
                af[mf][ks], bg[nf][ks], acc[(MH) * 4 + mf][(NH) * 2 + nf], 0,0,0);\
    __builtin_amdgcn_s_setprio(0);                                                \
    __builtin_amdgcn_sched_barrier(0);                                            \
    __builtin_amdgcn_s_barrier();                                                 \
    __builtin_amdgcn_sched_barrier(0);                                            \
}while(0)

__global__ __launch_bounds__(512) void gemm_energy_8ph(
    const u16* __restrict__ kb, const u16* __restrict__ Wt,
    const float* __restrict__ b_mono, const float* __restrict__ b_chunk,
    const float* __restrict__ vnorm, const float* __restrict__ v_chunk,
    const float* __restrict__ qp_mono, const float* __restrict__ qp_chunk,
    float* __restrict__ e_mono, float* __restrict__ e_chunk)
{
    __shared__ __align__(16) u16 SH[65536];   // 128 KiB: 2 buf x (A 256x64 + B 256x64) bf16

    const int bid = blockIdx.x;
    const int swz = (bid & 7) * 125 + (bid >> 3);   // XCD swizzle, bijective (1000 % 8 == 0)
    const int xt = swz >> 2;
    const int nT = swz & 3;
    const int g0 = xt * 256;
    const int n0 = nT * 256;

    const int tid = threadIdx.x;
    const int lane = tid & 63;
    const int wave = tid >> 6;
    const int wm = wave >> 2, wn = wave & 3;        // 2M x 4N waves
    const int l15 = lane & 15, quad = lane >> 4;

    // ---- preload all epilogue scalars BEFORE any staging (keeps vmcnt clean) ----
    const bool mono = (nT < 2);
    const float* qp = mono ? qp_mono : qp_chunk;
    float* edst = mono ? e_mono : e_chunk;
    float vv[4], bb[4]; float qA[4], qB[4];
    const int b0 = g0 / 4000;
    const int b1 = (g0 + 255) / 4000;               // b0 or b0+1
#pragma unroll
    for (int nf = 0; nf < 4; nf++){
        int c = (n0 - (mono ? 0 : 512)) + wn * 64 + nf * 16 + l15;
        vv[nf] = mono ? vnorm[c] : v_chunk[c];
        bb[nf] = mono ? b_mono[c] : b_chunk[c];
        qA[nf] = qp[b0 * 512 + c];
        qB[nf] = qp[b1 * 512 + c];
    }

    f32x4 acc[8][4];
#pragma unroll
    for (int i = 0; i < 8; i++)
#pragma unroll
        for (int j = 0; j < 4; j++)
#pragma unroll
            for (int c = 0; c < 4; c++) acc[i][j][c] = 0.f;

    // drain the preload traffic so stage drains see only glls
    DRAIN0;
    __builtin_amdgcn_sched_barrier(0);

    // ---- prologue: stage tile 0 -> buf0 fully, land it ----
    stageA(kb, SH, g0, 0, 0, tid);
    stageA(kb, SH, g0, 0, 1, tid);
    stageB(Wt, SH, n0, 0, 0, tid);
    stageB(Wt, SH, n0, 0, 1, tid);
    DRAIN0;
    __builtin_amdgcn_sched_barrier(0);
    __builtin_amdgcn_s_barrier();
    __builtin_amdgcn_sched_barrier(0);

    // ---- steady iterations: tiles E=2it (buf0, P1-P4), O=2it+1 (buf1, P5-P8) ----
    // P1: stage tile O -> buf1 (buf1 dead since prev-P8).  Drain P4 (3 phases old).
    // P5: stage tile E+2 -> buf0 (buf0 dead since P4).     Drain P8 (3 phases old).
#pragma unroll 1
    for (int it = 0; it < 4; it++){
        const int O = 2 * it + 1;
        const int Ep = 2 * it + 2;
        PHASE(0, 0, 0, { stageA(kb, SH, g0, O, 0, tid); stageA(kb, SH, g0, O, 1, tid);
                         stageB(Wt, SH, n0, O, 0, tid); stageB(Wt, SH, n0, O, 1, tid); },
              NODRAIN);
        PHASE(0, 0, 1, NOSTAGE, NODRAIN);
        PHASE(0, 1, 0, NOSTAGE, NODRAIN);
        PHASE(0, 1, 1, NOSTAGE, DRAIN0);
        PHASE(1, 0, 0, { if (it < 3){
                             stageA(kb, SH, g0, Ep, 0, tid); stageA(kb, SH, g0, Ep, 1, tid);
                             stageB(Wt, SH, n0, Ep, 0, tid); stageB(Wt, SH, n0, Ep, 1, tid); } },
              NODRAIN);
        PHASE(1, 0, 1, NOSTAGE, NODRAIN);
        PHASE(1, 1, 0, NOSTAGE, NODRAIN);
        PHASE(1, 1, 1, NOSTAGE, DRAIN0);
    }

    // ---- epilogue: e[row] += sum_cols v[col] * tanh(C + bias[col] + qproj[b][col]) ----
#pragma unroll
    for (int mf = 0; mf < 8; mf++){
#pragma unroll
        for (int r = 0; r < 4; r++){
            int g = g0 + wm * 128 + mf * 16 + quad * 4 + r;
            int bidx = (u32)g / 4000u;
            float s = 0.f;
#pragma unroll
            for (int nf = 0; nf < 4; nf++){
                float qv = (bidx == b0) ? qA[nf] : qB[nf];
                float x = acc[mf][nf][r] + bb[nf] + qv;
                s += vv[nf] * tanh_fast(x);
            }
            s += __shfl_xor(s, 1);
            s += __shfl_xor(s, 2);
            s += __shfl_xor(s, 4);
            s += __shfl_xor(s, 8);
            if (l15 == 0) atomicAdd(&edst[g], s);
        }
    }
}

// ---------------- fallback GEMM (small workspace): convert f32 key in-kernel ----------------
__global__ __launch_bounds__(256) void gemm_energy_f32(
    const float* __restrict__ key, const u16* __restrict__ Wt,
    const float* __restrict__ b_mono, const float* __restrict__ b_chunk,
    const float* __restrict__ vnorm, const float* __restrict__ v_chunk,
    const float* __restrict__ qp_mono, const float* __restrict__ qp_chunk,
    float* __restrict__ e_mono, float* __restrict__ e_chunk)
{
    __shared__ __align__(16) u16 As[128 * 40];
    __shared__ __align__(16) u16 Bs[128 * 40];
    const int tid = threadIdx.x;
    const int g0 = blockIdx.x * 128;
    const int nT = blockIdx.y;
    const bool mono = (nT < 4);
    const int n0 = nT * 128;
    const int lane = tid & 63;
    const int wave = tid >> 6;
    const int wm = wave >> 1, wn = wave & 1;
    const int l15 = lane & 15, quad = lane >> 4;

    f32x4 acc[4][4];
#pragma unroll
    for (int i = 0; i < 4; i++)
#pragma unroll
        for (int j = 0; j < 4; j++)
#pragma unroll
            for (int c = 0; c < 4; c++) acc[i][j][c] = 0.f;

    for (int k0 = 0; k0 < 512; k0 += 32){
        __syncthreads();
#pragma unroll
        for (int it = 0; it < 4; it++){
            int vid = tid + it * 256;
            int row = vid >> 3;
            int c4  = (vid & 7) << 2;
            float4 a = *reinterpret_cast<const float4*>(key + (size_t)(g0 + row) * 512 + k0 + c4);
            u32 p0 = (u32)f2bf(fmaxf(a.x, 0.f)) | ((u32)f2bf(fmaxf(a.y, 0.f)) << 16);
            u32 p1 = (u32)f2bf(fmaxf(a.z, 0.f)) | ((u32)f2bf(fmaxf(a.w, 0.f)) << 16);
            uint2 pk; pk.x = p0; pk.y = p1;
            *reinterpret_cast<uint2*>(&As[row * 40 + c4]) = pk;
        }
#pragma unroll
        for (int it = 0; it < 2; it++){
            int vid = tid + it * 256;
            int row = vid >> 2;
            int cb  = (vid & 3) << 3;
            uint4 b = *reinterpret_cast<const uint4*>(Wt + (size_t)(n0 + row) * 512 + k0 + cb);
            *reinterpret_cast<uint4*>(&Bs[row * 40 + cb]) = b;
        }
        __syncthreads();
        bf16x8 af[4], bfr[4];
#pragma unroll
        for (int i = 0; i < 4; i++){
            af[i]  = *reinterpret_cast<const bf16x8*>(&As[(wm * 64 + i * 16 + l15) * 40 + quad * 8]);
            bfr[i] = *reinterpret_cast<const bf16x8*>(&Bs[(wn * 64 + i * 16 + l15) * 40 + quad * 8]);
        }
#pragma unroll
        for (int i = 0; i < 4; i++)
#pragma unroll
            for (int j = 0; j < 4; j++)
                acc[i][j] = __builtin_amdgcn_mfma_f32_16x16x32_bf16(af[i], bfr[j], acc[i][j], 0, 0, 0);
    }

    const float* qp = mono ? qp_mono : qp_chunk;
    float* edst = mono ? e_mono : e_chunk;
    float vv[4], bb[4]; int nc[4];
#pragma unroll
    for (int j = 0; j < 4; j++){
        int ncol = (n0 - (mono ? 0 : 512)) + wn * 64 + j * 16 + l15;
        nc[j] = ncol;
        vv[j] = mono ? vnorm[ncol] : v_chunk[ncol];
        bb[j] = mono ? b_mono[ncol] : b_chunk[ncol];
    }
#pragma unroll
    for (int i = 0; i < 4; i++){
#pragma unroll
        for (int r = 0; r < 4; r++){
            int g = g0 + wm * 64 + i * 16 + quad * 4 + r;
            int bidx = (u32)g / 4000u;
            float s = 0.f;
#pragma unroll
            for (int j = 0; j < 4; j++){
                float x = acc[i][j][r] + bb[j] + qp[bidx * 512 + nc[j]];
                s += vv[j] * tanh_fast(x);
            }
            s += __shfl_xor(s, 1);
            s += __shfl_xor(s, 2);
            s += __shfl_xor(s, 4);
            s += __shfl_xor(s, 8);
            if (l15 == 0) atomicAdd(&edst[g], s);
        }
    }
}

// ---------------- per-batch scan: noise, p, alpha, chunk softmax, beta ----------------
#define IDX(t) ((t) + ((t) >> 4))

__global__ __launch_bounds__(256) void scan_energy(
    const float* __restrict__ e_mono, const float* __restrict__ e_chunk,
    const int* __restrict__ mask, const float* __restrict__ r_mono,
    float* __restrict__ out_alpha, float* __restrict__ beta)
{
    __shared__ float P[4256];
    __shared__ float AL[4256];
    __shared__ float SE[4256];
    __shared__ float red[256];
    const int b = blockIdx.x;
    const int tid = threadIdx.x;
    const float r = r_mono[0];
    const int t0 = tid * 16;

    float l[16];
    float lsum = 0.f;
#pragma unroll
    for (int i = 0; i < 16; i++){
        int t = t0 + i;
        if (t < T_LEN){
            int fl = b * T_LEN + t;
            float e = e_mono[fl] + r;
            if (mask[fl] == 0) e = NEG_INF;
            float x = e + jax_noise((u32)fl);
            float p = 1.0f / (1.0f + expf(-x));
            P[IDX(t)] = p;
            float om = 1.0f - p;
            om = fminf(fmaxf(om, 1e-6f), 1.0f);
            l[i] = logf(om);
            lsum += l[i];
        } else l[i] = 0.f;
    }
    red[tid] = lsum;
    __syncthreads();
#pragma unroll
    for (int off = 1; off < 256; off <<= 1){
        float v = (tid >= off) ? red[tid - off] : 0.f;
        __syncthreads();
        red[tid] += v;
        __syncthreads();
    }
    float run = red[tid] - lsum;
#pragma unroll
    for (int i = 0; i < 16; i++){
        int t = t0 + i;
        if (t < T_LEN){
            float alpha = P[IDX(t)] * expf(run);
            run += l[i];
            AL[IDX(t)] = alpha;
            out_alpha[b * T_LEN + t] = alpha;
        }
    }

    float ec[16]; float lmax = NEG_INF;
#pragma unroll
    for (int i = 0; i < 16; i++){
        int t = t0 + i;
        if (t < T_LEN){
            int fl = b * T_LEN + t;
            float e = e_chunk[fl];
            if (mask[fl] == 0) e = NEG_INF;
            ec[i] = e;
            lmax = fmaxf(lmax, e);
        } else ec[i] = NEG_INF;
    }
    __syncthreads();
    red[tid] = lmax;
    __syncthreads();
    for (int off = 128; off >= 1; off >>= 1){
        if (tid < off) red[tid] = fmaxf(red[tid], red[tid + off]);
        __syncthreads();
    }
    float m = red[0];
#pragma unroll
    for (int i = 0; i < 16; i++){
        int t = t0 + i;
        if (t < T_LEN) SE[IDX(t)] = fmaxf(expf(ec[i] - m), 1e-5f);
    }
    __syncthreads();
#pragma unroll
    for (int i = 0; i < 16; i++){
        int t = t0 + i;
        if (t < T_LEN){
            float d = 0.f;
            int lo = t - 7; if (lo < 0) lo = 0;
            for (int s = lo; s <= t; s++) d += SE[IDX(s)];
            P[IDX(t)] = AL[IDX(t)] / d;
        }
    }
    __syncthreads();
#pragma unroll
    for (int i = 0; i < 16; i++){
        int t = t0 + i;
        if (t < T_LEN){
            float s2 = 0.f;
            int hi = t + 7; if (hi > T_LEN - 1) hi = T_LEN - 1;
            for (int s = t; s <= hi; s++) s2 += P[IDX(s)];
            beta[b * T_LEN + t] = SE[IDX(t)] * s2;
        }
    }
}

// ---------------- cv = sum_t beta[t] * value[t,:] (into d_out directly) ----------------
__global__ __launch_bounds__(256) void cv_accum(const float* __restrict__ value,
                                                const float* __restrict__ beta,
                                                float* __restrict__ outcv){
    const int b = blockIdx.x >> 4;
    const int c = blockIdx.x & 15;
    const int tid = threadIdx.x;
    __shared__ float bsh[250];
    int tstart = c * 250;
    if (tid < 250) bsh[tid] = beta[b * T_LEN + tstart + tid];
    __syncthreads();
    int dl = (tid & 127) * 4;
    int trow = tid >> 7;
    float4 a = {0.f, 0.f, 0.f, 0.f};
    for (int t = trow; t < 250; t += 2){
        float bt = bsh[t];
        float4 v = *reinterpret_cast<const float4*>(
            value + (size_t)(b * T_LEN + tstart + t) * 512 + dl);
        a.x += bt * v.x; a.y += bt * v.y; a.z += bt * v.z; a.w += bt * v.w;
    }
    atomicAdd(&outcv[b * 512 + dl + 0], a.x);
    atomicAdd(&outcv[b * 512 + dl + 1], a.y);
    atomicAdd(&outcv[b * 512 + dl + 2], a.z);
    atomicAdd(&outcv[b * 512 + dl + 3], a.w);
}

// ---------------- launch ----------------
extern "C" void kernel_launch(void* const* d_in, const int* in_sizes, int n_in,
                              void* d_out, int out_size, void* d_ws, size_t ws_size,
                              hipStream_t stream)
{
    const float* key      = (const float*)d_in[0];
    const float* value    = (const float*)d_in[1];
    const float* query    = (const float*)d_in[2];
    const int*   mask     = (const int*)d_in[3];
    const float* wk_mono  = (const float*)d_in[4];
    const float* bk_mono  = (const float*)d_in[5];
    const float* wq_mono  = (const float*)d_in[6];
    const float* v_mono   = (const float*)d_in[7];
    const float* g_mono   = (const float*)d_in[8];
    const float* r_mono   = (const float*)d_in[9];
    const float* wk_chunk = (const float*)d_in[10];
    const float* bk_chunk = (const float*)d_in[11];
    const float* wq_chunk = (const float*)d_in[12];
    const float* v_chunk  = (const float*)d_in[13];

    float* ws      = (float*)d_ws;
    float* e_mono  = ws;                 // 64000
    float* e_chunk = ws + 64000;         // 64000
    float* beta    = ws + 136192;        // 64000
    float* qp_mono = ws + 200192;        // 8192
    float* qp_chunk= ws + 208384;        // 8192
    float* vnorm   = ws + 216576;        // 512
    u16*   Wt      = (u16*)(ws + 217088);// 1024x512 bf16 (1 MB)
    u16*   kb      = (u16*)(ws + 479232);// 64000x512 bf16 (65.5 MB) if it fits

    const size_t NEED = 479232u * 4u + (size_t)64000 * 512 * 2;
    const bool big = ws_size >= NEED;

    prep_combined<<<big ? 8612 : 612, 512, 0, stream>>>(
        v_mono, g_mono, query, wq_mono, wq_chunk, wk_mono, wk_chunk, key,
        vnorm, qp_mono, qp_chunk, Wt, kb, e_mono, (float*)d_out);

    if (big){
        gemm_energy_8ph<<<1000, 512, 0, stream>>>(kb, Wt, bk_mono, bk_chunk,
                                                  vnorm, v_chunk, qp_mono, qp_chunk,
                                                  e_mono, e_chunk);
    } else {
        gemm_energy_f32<<<dim3(500, 8), 256, 0, stream>>>(key, Wt, bk_mono, bk_chunk,
                                                          vnorm, v_chunk, qp_mono, qp_chunk,
                                                          e_mono, e_chunk);
    }
    scan_energy<<<16, 256, 0, stream>>>(e_mono, e_chunk, mask, r_mono,
                                        (float*)d_out + 8192, beta);
    cv_accum<<<256, 256, 0, stream>>>(value, beta, (float*)d_out);
}

// Round 4
// 472.686 us; speedup vs baseline: 1.1268x; 1.1268x over previous
//
#include <hip/hip_runtime.h>
#include <stdint.h>

typedef unsigned short u16;
typedef unsigned int   u32;

#define T_LEN 4000
#define NEG_INF (-3.4028234663852886e38f)

typedef __bf16 bf16x8 __attribute__((ext_vector_type(8)));
typedef float  f32x4  __attribute__((ext_vector_type(4)));

__device__ __forceinline__ u16 f2bf(float f){
    union { float f; u32 i; } v; v.f = f;
    u32 u = v.i;
    u32 r = (u + 0x7FFFu + ((u >> 16) & 1u)) >> 16;
    return (u16)r;
}
__device__ __forceinline__ float tanh_fast(float x){
    float ax = fabsf(x);
    float a = __expf(-2.0f * ax);
    float t = (1.0f - a) / (1.0f + a);
    return copysignf(t, x);
}
__device__ __forceinline__ u32 rotl32(u32 x, int n){ return (x << n) | (x >> (32 - n)); }

// async global->LDS, 16B per lane (global_load_lds_dwordx4).
// LDS dest must be linear in lane order: base + lane*16.
__device__ __forceinline__ void gll16(const void* g, void* l){
    __builtin_amdgcn_global_load_lds(
        (__attribute__((address_space(1))) void*)g,
        (__attribute__((address_space(3))) void*)l, 16, 0, 0);
}

// jax.random.normal(jax.random.key(123), (16,4000), f32) — threefry2x32. [verified]
__device__ float jax_noise(u32 idx){
    const u32 k0 = 0u, k1 = 123u;
    const u32 k2 = k0 ^ k1 ^ 0x1BD11BDAu;
    u32 x0 = k0;
    u32 x1 = idx + k1;
#define RND(r) { x0 += x1; x1 = rotl32(x1, r); x1 ^= x0; }
    RND(13) RND(15) RND(26) RND(6)   x0 += k1; x1 += k2 + 1u;
    RND(17) RND(29) RND(16) RND(24)  x0 += k2; x1 += k0 + 2u;
    RND(13) RND(15) RND(26) RND(6)   x0 += k0; x1 += k1 + 3u;
    RND(17) RND(29) RND(16) RND(24)  x0 += k1; x1 += k2 + 4u;
    RND(13) RND(15) RND(26) RND(6)   x0 += k2; x1 += k0 + 5u;
#undef RND
    u32 bits = x0 ^ x1;
    union { u32 i; float f; } u;
    u.i = (bits >> 9) | 0x3F800000u;
    float f01 = u.f - 1.0f;
    const float minval = -0.99999994f;
    float uu = f01 * (1.0f - minval) + minval;
    uu = fmaxf(uu, minval);
    return 1.41421356f * erfinvf(uu);
}

// ---------------- merged prep: vnorm, qproj, W transpose, zeroing, key->bf16 ----------------
__global__ __launch_bounds__(512) void prep_combined(
    const float* __restrict__ v_mono, const float* __restrict__ g_mono,
    const float* __restrict__ query, const float* __restrict__ wq_mono,
    const float* __restrict__ wq_chunk,
    const float* __restrict__ wk_mono, const float* __restrict__ wk_chunk,
    const float* __restrict__ key,
    float* __restrict__ vn, float* __restrict__ qp_mono, float* __restrict__ qp_chunk,
    u16* __restrict__ Wt, u16* __restrict__ kb,
    float* __restrict__ ezero, float* __restrict__ outcv)
{
    __shared__ float shf[512];
    __shared__ u16 tile[32][33];
    const int blk = blockIdx.x;
    const int tid = threadIdx.x;
    if (blk == 0){
        float v = v_mono[tid];
        shf[tid] = v * v;
        __syncthreads();
        for (int off = 256; off >= 1; off >>= 1){
            if (tid < off) shf[tid] += shf[tid + off];
            __syncthreads();
        }
        float g = g_mono[0];
        vn[tid] = g * v / sqrtf(shf[0]);
    } else if (blk <= 32){
        int b = (blk - 1) >> 1;
        int which = (blk - 1) & 1;
        const float* W = which ? wq_chunk : wq_mono;
        float* out = which ? qp_chunk : qp_mono;
        shf[tid] = query[b * 512 + tid];
        __syncthreads();
        float acc = 0.f;
        for (int k = 0; k < 512; k++) acc += shf[k] * W[k * 512 + tid];
        out[b * 512 + tid] = acc;
    } else if (blk <= 544){
        int idx = blk - 33;                     // 0..511
        int kt = (idx & 15) * 32, nt = (idx >> 4) * 32;
        int c = tid & 31, r = tid >> 5;         // 32 cols x 16 rows
        const float* src = (nt < 512) ? wk_mono : wk_chunk;
        int nbase = (nt < 512) ? nt : nt - 512;
#pragma unroll
        for (int i = 0; i < 2; i++){
            int kk = r + i * 16;
            tile[kk][c] = f2bf(src[(size_t)(kt + kk) * 512 + nbase + c]);
        }
        __syncthreads();
#pragma unroll
        for (int i = 0; i < 2; i++){
            int nn = r + i * 16;
            Wt[(size_t)(nt + nn) * 512 + kt + c] = tile[c][nn];
        }
    } else if (blk < 608){
        int i = ((blk - 545) * 512 + tid) * 4;   // zero e_mono|e_chunk (128000 floats)
        if (i < 128000){
            float4 z = {0.f, 0.f, 0.f, 0.f};
            *reinterpret_cast<float4*>(ezero + i) = z;
        }
    } else if (blk < 612){
        int i = ((blk - 608) * 512 + tid) * 4;   // zero cv accum target (8192 floats)
        float4 z = {0.f, 0.f, 0.f, 0.f};
        *reinterpret_cast<float4*>(outcv + i) = z;
    } else {
        size_t i = ((size_t)(blk - 612) * 512 + tid) * 8;
        float4 a = *reinterpret_cast<const float4*>(key + i);
        float4 b = *reinterpret_cast<const float4*>(key + i + 4);
        uint4 pk;
        pk.x = (u32)f2bf(fmaxf(a.x, 0.f)) | ((u32)f2bf(fmaxf(a.y, 0.f)) << 16);
        pk.y = (u32)f2bf(fmaxf(a.z, 0.f)) | ((u32)f2bf(fmaxf(a.w, 0.f)) << 16);
        pk.z = (u32)f2bf(fmaxf(b.x, 0.f)) | ((u32)f2bf(fmaxf(b.y, 0.f)) << 16);
        pk.w = (u32)f2bf(fmaxf(b.z, 0.f)) | ((u32)f2bf(fmaxf(b.w, 0.f)) << 16);
        *reinterpret_cast<uint4*>(kb + i) = pk;
    }
}

// ---------------- main GEMM + energy epilogue (m97 2-phase, BK=64, swizzled LDS) ----------------
// 128x128 tile, 4 waves, BK=64 (8 K-steps, half the barrier drains of BK=32).
// gll16 staging into linear LDS with XOR pre-swizzle on the global source;
// ds_read applies the same XOR -> conflict-free (verified 0 conflicts in R3 geometry).
__global__ __launch_bounds__(256) void gemm_energy_pre(
    const u16* __restrict__ kb, const u16* __restrict__ Wt,
    const float* __restrict__ b_mono, const float* __restrict__ b_chunk,
    const float* __restrict__ vnorm, const float* __restrict__ v_chunk,
    const float* __restrict__ qp_mono, const float* __restrict__ qp_chunk,
    float* __restrict__ e_mono, float* __restrict__ e_chunk)
{
    __shared__ __align__(16) u16 As[128 * 64];   // 16 KiB
    __shared__ __align__(16) u16 Bs[128 * 64];   // 16 KiB
    const int bid = blockIdx.x;
    const int x = ((bid >> 6) << 3) + (bid & 7);  // 8 nT sharing an A-tile adjacent + same XCD
    if (x >= 500) return;
    const int nT = (bid >> 3) & 7;
    const int g0 = x * 128;
    const bool mono = (nT < 4);
    const int n0 = nT * 128;
    const int tid = threadIdx.x;
    const int lane = tid & 63;
    const int wave = tid >> 6;
    const int wm = wave >> 1, wn = wave & 1;
    const int l15 = lane & 15, quad = lane >> 4;

    f32x4 acc[4][4];
#pragma unroll
    for (int i = 0; i < 4; i++)
#pragma unroll
        for (int j = 0; j < 4; j++)
#pragma unroll
            for (int c = 0; c < 4; c++) acc[i][j][c] = 0.f;

    const u16* aG = kb + (size_t)g0 * 512;
    const u16* bG = Wt + (size_t)n0 * 512;

    for (int k0 = 0; k0 < 512; k0 += 64){
        __syncthreads();          // prior iter's ds_reads done before overwrite
        // stage: 128 rows x 64 bf16 each = 1024 x 16B slots; 4 slots/thread/matrix.
        // LDS linear (vid*16B); global source pre-swizzled: slot sl = (vid&7)^(row&7).
#pragma unroll
        for (int it = 0; it < 4; it++){
            int vid = tid + it * 256;        // 0..1023
            int row = vid >> 3;              // 0..127
            int sl  = (vid & 7) ^ (row & 7);
            gll16(aG + (size_t)row * 512 + k0 + sl * 8, As + vid * 8);
            gll16(bG + (size_t)row * 512 + k0 + sl * 8, Bs + vid * 8);
        }
        __syncthreads();          // compiler emits vmcnt(0) drain: tiles complete
        bf16x8 af[4][2], bfr[4][2];
#pragma unroll
        for (int i = 0; i < 4; i++)
#pragma unroll
            for (int ks = 0; ks < 2; ks++){
                int ra = wm * 64 + i * 16 + l15;
                af[i][ks]  = *reinterpret_cast<const bf16x8*>(
                    &As[ra * 64 + (((ks * 4 + quad) ^ (ra & 7)) << 3)]);
                int rb = wn * 64 + i * 16 + l15;
                bfr[i][ks] = *reinterpret_cast<const bf16x8*>(
                    &Bs[rb * 64 + (((ks * 4 + quad) ^ (rb & 7)) << 3)]);
            }
#pragma unroll
        for (int i = 0; i < 4; i++)
#pragma unroll
            for (int j = 0; j < 4; j++)
#pragma unroll
                for (int ks = 0; ks < 2; ks++)
                    acc[i][j] = __builtin_amdgcn_mfma_f32_16x16x32_bf16(
                        af[i][ks], bfr[j][ks], acc[i][j], 0, 0, 0);
    }

    // epilogue: e[row] += sum_cols v[col] * tanh(C + bias[col] + qproj[b][col])
    const float* qp = mono ? qp_mono : qp_chunk;
    float* edst = mono ? e_mono : e_chunk;
    float vv[4], bb[4]; int nc[4];
#pragma unroll
    for (int j = 0; j < 4; j++){
        int ncol = (n0 - (mono ? 0 : 512)) + wn * 64 + j * 16 + l15;
        nc[j] = ncol;
        vv[j] = mono ? vnorm[ncol] : v_chunk[ncol];
        bb[j] = mono ? b_mono[ncol] : b_chunk[ncol];
    }
#pragma unroll
    for (int i = 0; i < 4; i++){
#pragma unroll
        for (int r = 0; r < 4; r++){
            int g = g0 + wm * 64 + i * 16 + quad * 4 + r;    // C/D: row = quad*4+reg
            int bidx = (u32)g / 4000u;
            float s = 0.f;
#pragma unroll
            for (int j = 0; j < 4; j++){
                float x2 = acc[i][j][r] + bb[j] + qp[bidx * 512 + nc[j]];
                s += vv[j] * tanh_fast(x2);
            }
            s += __shfl_xor(s, 1);
            s += __shfl_xor(s, 2);
            s += __shfl_xor(s, 4);
            s += __shfl_xor(s, 8);
            if (l15 == 0) atomicAdd(&edst[g], s);
        }
    }
}

// ---------------- fallback GEMM (small workspace): convert f32 key in-kernel ----------------
__global__ __launch_bounds__(256) void gemm_energy_f32(
    const float* __restrict__ key, const u16* __restrict__ Wt,
    const float* __restrict__ b_mono, const float* __restrict__ b_chunk,
    const float* __restrict__ vnorm, const float* __restrict__ v_chunk,
    const float* __restrict__ qp_mono, const float* __restrict__ qp_chunk,
    float* __restrict__ e_mono, float* __restrict__ e_chunk)
{
    __shared__ __align__(16) u16 As[128 * 40];
    __shared__ __align__(16) u16 Bs[128 * 40];
    const int tid = threadIdx.x;
    const int g0 = blockIdx.x * 128;
    const int nT = blockIdx.y;
    const bool mono = (nT < 4);
    const int n0 = nT * 128;
    const int lane = tid & 63;
    const int wave = tid >> 6;
    const int wm = wave >> 1, wn = wave & 1;
    const int l15 = lane & 15, quad = lane >> 4;

    f32x4 acc[4][4];
#pragma unroll
    for (int i = 0; i < 4; i++)
#pragma unroll
        for (int j = 0; j < 4; j++)
#pragma unroll
            for (int c = 0; c < 4; c++) acc[i][j][c] = 0.f;

    for (int k0 = 0; k0 < 512; k0 += 32){
        __syncthreads();
#pragma unroll
        for (int it = 0; it < 4; it++){
            int vid = tid + it * 256;
            int row = vid >> 3;
            int c4  = (vid & 7) << 2;
            float4 a = *reinterpret_cast<const float4*>(key + (size_t)(g0 + row) * 512 + k0 + c4);
            u32 p0 = (u32)f2bf(fmaxf(a.x, 0.f)) | ((u32)f2bf(fmaxf(a.y, 0.f)) << 16);
            u32 p1 = (u32)f2bf(fmaxf(a.z, 0.f)) | ((u32)f2bf(fmaxf(a.w, 0.f)) << 16);
            uint2 pk; pk.x = p0; pk.y = p1;
            *reinterpret_cast<uint2*>(&As[row * 40 + c4]) = pk;
        }
#pragma unroll
        for (int it = 0; it < 2; it++){
            int vid = tid + it * 256;
            int row = vid >> 2;
            int cb  = (vid & 3) << 3;
            uint4 b = *reinterpret_cast<const uint4*>(Wt + (size_t)(n0 + row) * 512 + k0 + cb);
            *reinterpret_cast<uint4*>(&Bs[row * 40 + cb]) = b;
        }
        __syncthreads();
        bf16x8 af[4], bfr[4];
#pragma unroll
        for (int i = 0; i < 4; i++){
            af[i]  = *reinterpret_cast<const bf16x8*>(&As[(wm * 64 + i * 16 + l15) * 40 + quad * 8]);
            bfr[i] = *reinterpret_cast<const bf16x8*>(&Bs[(wn * 64 + i * 16 + l15) * 40 + quad * 8]);
        }
#pragma unroll
        for (int i = 0; i < 4; i++)
#pragma unroll
            for (int j = 0; j < 4; j++)
                acc[i][j] = __builtin_amdgcn_mfma_f32_16x16x32_bf16(af[i], bfr[j], acc[i][j], 0, 0, 0);
    }

    const float* qp = mono ? qp_mono : qp_chunk;
    float* edst = mono ? e_mono : e_chunk;
    float vv[4], bb[4]; int nc[4];
#pragma unroll
    for (int j = 0; j < 4; j++){
        int ncol = (n0 - (mono ? 0 : 512)) + wn * 64 + j * 16 + l15;
        nc[j] = ncol;
        vv[j] = mono ? vnorm[ncol] : v_chunk[ncol];
        bb[j] = mono ? b_mono[ncol] : b_chunk[ncol];
    }
#pragma unroll
    for (int i = 0; i < 4; i++){
#pragma unroll
        for (int r = 0; r < 4; r++){
            int g = g0 + wm * 64 + i * 16 + quad * 4 + r;
            int bidx = (u32)g / 4000u;
            float s = 0.f;
#pragma unroll
            for (int j = 0; j < 4; j++){
                float x = acc[i][j][r] + bb[j] + qp[bidx * 512 + nc[j]];
                s += vv[j] * tanh_fast(x);
            }
            s += __shfl_xor(s, 1);
            s += __shfl_xor(s, 2);
            s += __shfl_xor(s, 4);
            s += __shfl_xor(s, 8);
            if (l15 == 0) atomicAdd(&edst[g], s);
        }
    }
}

// ---------------- per-batch scan: noise, p, alpha, chunk softmax, beta ----------------
// 512 threads (8 elems each): halves the serial transcendental chain per thread.
#define IDX(t) ((t) + ((t) >> 4))

__global__ __launch_bounds__(512) void scan_energy(
    const float* __restrict__ e_mono, const float* __restrict__ e_chunk,
    const int* __restrict__ mask, const float* __restrict__ r_mono,
    float* __restrict__ out_alpha, float* __restrict__ beta)
{
    __shared__ float P[4256];
    __shared__ float AL[4256];
    __shared__ float SE[4256];
    __shared__ float red[512];
    const int b = blockIdx.x;
    const int tid = threadIdx.x;
    const float r = r_mono[0];
    const int t0 = tid * 8;

    float l[8];
    float lsum = 0.f;
#pragma unroll
    for (int i = 0; i < 8; i++){
        int t = t0 + i;
        if (t < T_LEN){
            int fl = b * T_LEN + t;
            float e = e_mono[fl] + r;
            if (mask[fl] == 0) e = NEG_INF;
            float x = e + jax_noise((u32)fl);
            float p = 1.0f / (1.0f + expf(-x));
            P[IDX(t)] = p;
            float om = 1.0f - p;
            om = fminf(fmaxf(om, 1e-6f), 1.0f);
            l[i] = logf(om);
            lsum += l[i];
        } else l[i] = 0.f;
    }
    red[tid] = lsum;
    __syncthreads();
#pragma unroll
    for (int off = 1; off < 512; off <<= 1){
        float v = (tid >= off) ? red[tid - off] : 0.f;
        __syncthreads();
        red[tid] += v;
        __syncthreads();
    }
    float run = red[tid] - lsum;
#pragma unroll
    for (int i = 0; i < 8; i++){
        int t = t0 + i;
        if (t < T_LEN){
            float alpha = P[IDX(t)] * expf(run);
            run += l[i];
            AL[IDX(t)] = alpha;
            out_alpha[b * T_LEN + t] = alpha;
        }
    }

    float ec[8]; float lmax = NEG_INF;
#pragma unroll
    for (int i = 0; i < 8; i++){
        int t = t0 + i;
        if (t < T_LEN){
            int fl = b * T_LEN + t;
            float e = e_chunk[fl];
            if (mask[fl] == 0) e = NEG_INF;
            ec[i] = e;
            lmax = fmaxf(lmax, e);
        } else ec[i] = NEG_INF;
    }
    __syncthreads();
    red[tid] = lmax;
    __syncthreads();
    for (int off = 256; off >= 1; off >>= 1){
        if (tid < off) red[tid] = fmaxf(red[tid], red[tid + off]);
        __syncthreads();
    }
    float m = red[0];
#pragma unroll
    for (int i = 0; i < 8; i++){
        int t = t0 + i;
        if (t < T_LEN) SE[IDX(t)] = fmaxf(expf(ec[i] - m), 1e-5f);
    }
    __syncthreads();
#pragma unroll
    for (int i = 0; i < 8; i++){
        int t = t0 + i;
        if (t < T_LEN){
            float d = 0.f;
            int lo = t - 7; if (lo < 0) lo = 0;
            for (int s = lo; s <= t; s++) d += SE[IDX(s)];
            P[IDX(t)] = AL[IDX(t)] / d;
        }
    }
    __syncthreads();
#pragma unroll
    for (int i = 0; i < 8; i++){
        int t = t0 + i;
        if (t < T_LEN){
            float s2 = 0.f;
            int hi = t + 7; if (hi > T_LEN - 1) hi = T_LEN - 1;
            for (int s = t; s <= hi; s++) s2 += P[IDX(s)];
            beta[b * T_LEN + t] = SE[IDX(t)] * s2;
        }
    }
}

// ---------------- cv = sum_t beta[t] * value[t,:] (into d_out directly) ----------------
__global__ __launch_bounds__(256) void cv_accum(const float* __restrict__ value,
                                                const float* __restrict__ beta,
                                                float* __restrict__ outcv){
    const int b = blockIdx.x >> 4;
    const int c = blockIdx.x & 15;
    const int tid = threadIdx.x;
    __shared__ float bsh[250];
    __shared__ float part[512];
    int tstart = c * 250;
    if (tid < 250) bsh[tid] = beta[b * T_LEN + tstart + tid];
    __syncthreads();
    int dl = (tid & 127) * 4;
    int trow = tid >> 7;
    float4 a = {0.f, 0.f, 0.f, 0.f};
    for (int t = trow; t < 250; t += 2){
        float bt = bsh[t];
        float4 v = *reinterpret_cast<const float4*>(
            value + (size_t)(b * T_LEN + tstart + t) * 512 + dl);
        a.x += bt * v.x; a.y += bt * v.y; a.z += bt * v.z; a.w += bt * v.w;
    }
    // pair-reduce trow 0/1 in LDS: halves same-address atomic traffic
    if (trow == 1){
        part[(tid & 127) * 4 + 0] = a.x;
        part[(tid & 127) * 4 + 1] = a.y;
        part[(tid & 127) * 4 + 2] = a.z;
        part[(tid & 127) * 4 + 3] = a.w;
    }
    __syncthreads();
    if (trow == 0){
        a.x += part[(tid & 127) * 4 + 0];
        a.y += part[(tid & 127) * 4 + 1];
        a.z += part[(tid & 127) * 4 + 2];
        a.w += part[(tid & 127) * 4 + 3];
        atomicAdd(&outcv[b * 512 + dl + 0], a.x);
        atomicAdd(&outcv[b * 512 + dl + 1], a.y);
        atomicAdd(&outcv[b * 512 + dl + 2], a.z);
        atomicAdd(&outcv[b * 512 + dl + 3], a.w);
    }
}

// ---------------- launch ----------------
extern "C" void kernel_launch(void* const* d_in, const int* in_sizes, int n_in,
                              void* d_out, int out_size, void* d_ws, size_t ws_size,
                              hipStream_t stream)
{
    const float* key      = (const float*)d_in[0];
    const float* value    = (const float*)d_in[1];
    const float* query    = (const float*)d_in[2];
    const int*   mask     = (const int*)d_in[3];
    const float* wk_mono  = (const float*)d_in[4];
    const float* bk_mono  = (const float*)d_in[5];
    const float* wq_mono  = (const float*)d_in[6];
    const float* v_mono   = (const float*)d_in[7];
    const float* g_mono   = (const float*)d_in[8];
    const float* r_mono   = (const float*)d_in[9];
    const float* wk_chunk = (const float*)d_in[10];
    const float* bk_chunk = (const float*)d_in[11];
    const float* wq_chunk = (const float*)d_in[12];
    const float* v_chunk  = (const float*)d_in[13];

    float* ws      = (float*)d_ws;
    float* e_mono  = ws;                 // 64000
    float* e_chunk = ws + 64000;         // 64000
    float* beta    = ws + 136192;        // 64000
    float* qp_mono = ws + 200192;        // 8192
    float* qp_chunk= ws + 208384;        // 8192
    float* vnorm   = ws + 216576;        // 512
    u16*   Wt      = (u16*)(ws + 217088);// 1024x512 bf16 (1 MB)
    u16*   kb      = (u16*)(ws + 479232);// 64000x512 bf16 (65.5 MB) if it fits

    const size_t NEED = 479232u * 4u + (size_t)64000 * 512 * 2;
    const bool big = ws_size >= NEED;

    prep_combined<<<big ? 8612 : 612, 512, 0, stream>>>(
        v_mono, g_mono, query, wq_mono, wq_chunk, wk_mono, wk_chunk, key,
        vnorm, qp_mono, qp_chunk, Wt, kb, e_mono, (float*)d_out);

    if (big){
        gemm_energy_pre<<<4096, 256, 0, stream>>>(kb, Wt, bk_mono, bk_chunk,
                                                  vnorm, v_chunk, qp_mono, qp_chunk,
                                                  e_mono, e_chunk);
    } else {
        gemm_energy_f32<<<dim3(500, 8), 256, 0, stream>>>(key, Wt, bk_mono, bk_chunk,
                                                          vnorm, v_chunk, qp_mono, qp_chunk,
                                                          e_mono, e_chunk);
    }
    scan_energy<<<16, 512, 0, stream>>>(e_mono, e_chunk, mask, r_mono,
                                        (float*)d_out + 8192, beta);
    cv_accum<<<256, 256, 0, stream>>>(value, beta, (float*)d_out);
}

// Round 5
// 453.954 us; speedup vs baseline: 1.1733x; 1.0413x over previous
//
#include <hip/hip_runtime.h>
#include <stdint.h>

typedef unsigned short u16;
typedef unsigned int   u32;

#define T_LEN 4000
#define NEG_INF (-3.4028234663852886e38f)

typedef __bf16 bf16x8 __attribute__((ext_vector_type(8)));
typedef float  f32x4  __attribute__((ext_vector_type(4)));

__device__ __forceinline__ u16 f2bf(float f){
    union { float f; u32 i; } v; v.f = f;
    u32 u = v.i;
    u32 r = (u + 0x7FFFu + ((u >> 16) & 1u)) >> 16;
    return (u16)r;
}
__device__ __forceinline__ float tanh_fast(float x){
    float ax = fabsf(x);
    float a = __expf(-2.0f * ax);
    float t = (1.0f - a) / (1.0f + a);
    return copysignf(t, x);
}
__device__ __forceinline__ u32 rotl32(u32 x, int n){ return (x << n) | (x >> (32 - n)); }

// async global->LDS, 16B per lane (global_load_lds_dwordx4).
// LDS dest must be linear in lane order: base + lane*16.
__device__ __forceinline__ void gll16(const void* g, void* l){
    __builtin_amdgcn_global_load_lds(
        (__attribute__((address_space(1))) void*)g,
        (__attribute__((address_space(3))) void*)l, 16, 0, 0);
}

// jax.random.normal(jax.random.key(123), (16,4000), f32) — threefry2x32. [verified]
__device__ float jax_noise(u32 idx){
    const u32 k0 = 0u, k1 = 123u;
    const u32 k2 = k0 ^ k1 ^ 0x1BD11BDAu;
    u32 x0 = k0;
    u32 x1 = idx + k1;
#define RND(r) { x0 += x1; x1 = rotl32(x1, r); x1 ^= x0; }
    RND(13) RND(15) RND(26) RND(6)   x0 += k1; x1 += k2 + 1u;
    RND(17) RND(29) RND(16) RND(24)  x0 += k2; x1 += k0 + 2u;
    RND(13) RND(15) RND(26) RND(6)   x0 += k0; x1 += k1 + 3u;
    RND(17) RND(29) RND(16) RND(24)  x0 += k1; x1 += k2 + 4u;
    RND(13) RND(15) RND(26) RND(6)   x0 += k2; x1 += k0 + 5u;
#undef RND
    u32 bits = x0 ^ x1;
    union { u32 i; float f; } u;
    u.i = (bits >> 9) | 0x3F800000u;
    float f01 = u.f - 1.0f;
    const float minval = -0.99999994f;
    float uu = f01 * (1.0f - minval) + minval;
    uu = fmaxf(uu, minval);
    return 1.41421356f * erfinvf(uu);
}

// ---------------- merged prep: vnorm, qproj, W transpose, zeroing, key->bf16 ----------------
__global__ __launch_bounds__(512) void prep_combined(
    const float* __restrict__ v_mono, const float* __restrict__ g_mono,
    const float* __restrict__ query, const float* __restrict__ wq_mono,
    const float* __restrict__ wq_chunk,
    const float* __restrict__ wk_mono, const float* __restrict__ wk_chunk,
    const float* __restrict__ key,
    float* __restrict__ vn, float* __restrict__ qp_mono, float* __restrict__ qp_chunk,
    u16* __restrict__ Wt, u16* __restrict__ kb,
    float* __restrict__ ezero, float* __restrict__ outcv)
{
    __shared__ float shf[512];
    __shared__ u16 tile[32][33];
    const int blk = blockIdx.x;
    const int tid = threadIdx.x;
    if (blk == 0){
        float v = v_mono[tid];
        shf[tid] = v * v;
        __syncthreads();
        for (int off = 256; off >= 1; off >>= 1){
            if (tid < off) shf[tid] += shf[tid + off];
            __syncthreads();
        }
        float g = g_mono[0];
        vn[tid] = g * v / sqrtf(shf[0]);
    } else if (blk <= 32){
        int b = (blk - 1) >> 1;
        int which = (blk - 1) & 1;
        const float* W = which ? wq_chunk : wq_mono;
        float* out = which ? qp_chunk : qp_mono;
        shf[tid] = query[b * 512 + tid];
        __syncthreads();
        float acc = 0.f;
        for (int k = 0; k < 512; k++) acc += shf[k] * W[k * 512 + tid];
        out[b * 512 + tid] = acc;
    } else if (blk <= 544){
        int idx = blk - 33;                     // 0..511
        int kt = (idx & 15) * 32, nt = (idx >> 4) * 32;
        int c = tid & 31, r = tid >> 5;         // 32 cols x 16 rows
        const float* src = (nt < 512) ? wk_mono : wk_chunk;
        int nbase = (nt < 512) ? nt : nt - 512;
#pragma unroll
        for (int i = 0; i < 2; i++){
            int kk = r + i * 16;
            tile[kk][c] = f2bf(src[(size_t)(kt + kk) * 512 + nbase + c]);
        }
        __syncthreads();
#pragma unroll
        for (int i = 0; i < 2; i++){
            int nn = r + i * 16;
            Wt[(size_t)(nt + nn) * 512 + kt + c] = tile[c][nn];
        }
    } else if (blk < 608){
        int i = ((blk - 545) * 512 + tid) * 4;   // zero e_mono|e_chunk (128000 floats)
        if (i < 128000){
            float4 z = {0.f, 0.f, 0.f, 0.f};
            *reinterpret_cast<float4*>(ezero + i) = z;
        }
    } else if (blk < 612){
        int i = ((blk - 608) * 512 + tid) * 4;   // zero cv accum target (8192 floats)
        float4 z = {0.f, 0.f, 0.f, 0.f};
        *reinterpret_cast<float4*>(outcv + i) = z;
    } else {
        size_t i = ((size_t)(blk - 612) * 512 + tid) * 8;
        float4 a = *reinterpret_cast<const float4*>(key + i);
        float4 b = *reinterpret_cast<const float4*>(key + i + 4);
        uint4 pk;
        pk.x = (u32)f2bf(fmaxf(a.x, 0.f)) | ((u32)f2bf(fmaxf(a.y, 0.f)) << 16);
        pk.y = (u32)f2bf(fmaxf(a.z, 0.f)) | ((u32)f2bf(fmaxf(a.w, 0.f)) << 16);
        pk.z = (u32)f2bf(fmaxf(b.x, 0.f)) | ((u32)f2bf(fmaxf(b.y, 0.f)) << 16);
        pk.w = (u32)f2bf(fmaxf(b.z, 0.f)) | ((u32)f2bf(fmaxf(b.w, 0.f)) << 16);
        *reinterpret_cast<uint4*>(kb + i) = pk;
    }
}

// ---------------- main GEMM + energy epilogue ----------------
// 128x128 tile, 4 waves, BK=64, DOUBLE-BUFFERED (T3 minimum-2-phase):
// stage tile k+1 into buf^1 BEFORE computing tile k from buf; single
// __syncthreads per iter (its vmcnt(0) drains loads that flew during compute).
// WAR-free: writes always target the buffer not being read this iteration.
// XOR swizzle both sides (R4-verified: 0 bank conflicts).
__global__ __launch_bounds__(256) void gemm_energy_pre(
    const u16* __restrict__ kb, const u16* __restrict__ Wt,
    const float* __restrict__ b_mono, const float* __restrict__ b_chunk,
    const float* __restrict__ vnorm, const float* __restrict__ v_chunk,
    const float* __restrict__ qp_mono, const float* __restrict__ qp_chunk,
    float* __restrict__ e_mono, float* __restrict__ e_chunk)
{
    __shared__ __align__(16) u16 As[2][128 * 64];   // 2 x 16 KiB
    __shared__ __align__(16) u16 Bs[2][128 * 64];   // 2 x 16 KiB (64 KiB total)
    const int bid = blockIdx.x;
    const int x = ((bid >> 6) << 3) + (bid & 7);  // 8 nT sharing an A-tile adjacent + same XCD
    if (x >= 500) return;
    const int nT = (bid >> 3) & 7;
    const int g0 = x * 128;
    const bool mono = (nT < 4);
    const int n0 = nT * 128;
    const int tid = threadIdx.x;
    const int lane = tid & 63;
    const int wave = tid >> 6;
    const int wm = wave >> 1, wn = wave & 1;
    const int l15 = lane & 15, quad = lane >> 4;

    f32x4 acc[4][4];
#pragma unroll
    for (int i = 0; i < 4; i++)
#pragma unroll
        for (int j = 0; j < 4; j++)
#pragma unroll
            for (int c = 0; c < 4; c++) acc[i][j][c] = 0.f;

    const u16* aG = kb + (size_t)g0 * 512;
    const u16* bG = Wt + (size_t)n0 * 512;

    // stage one BK=64 tile (A+B) into buffer `bsel`.
    // 1024 x 16B slots per matrix, 4 per thread; global source pre-swizzled.
#define STAGE(bsel, k0) do{                                                     \
    _Pragma("unroll") for (int it_ = 0; it_ < 4; it_++){                        \
        int vid = tid + it_ * 256;                                              \
        int row = vid >> 3;                                                     \
        int sl  = (vid & 7) ^ (row & 7);                                        \
        gll16(aG + (size_t)row * 512 + (k0) + sl * 8, &As[bsel][vid * 8]);      \
        gll16(bG + (size_t)row * 512 + (k0) + sl * 8, &Bs[bsel][vid * 8]);      \
    }                                                                           \
}while(0)

    STAGE(0, 0);
    __syncthreads();                   // drains vmcnt(0): tile 0 resident

#pragma unroll 1
    for (int kt = 0; kt < 8; kt++){
        const int cur = kt & 1;
        if (kt < 7) STAGE(cur ^ 1, (kt + 1) * 64);   // prefetch next tile, other buffer
        bf16x8 af[4][2], bfr[4][2];
#pragma unroll
        for (int i = 0; i < 4; i++)
#pragma unroll
            for (int ks = 0; ks < 2; ks++){
                int ra = wm * 64 + i * 16 + l15;
                af[i][ks]  = *reinterpret_cast<const bf16x8*>(
                    &As[cur][ra * 64 + (((ks * 4 + quad) ^ (ra & 7)) << 3)]);
                int rb = wn * 64 + i * 16 + l15;
                bfr[i][ks] = *reinterpret_cast<const bf16x8*>(
                    &Bs[cur][rb * 64 + (((ks * 4 + quad) ^ (rb & 7)) << 3)]);
            }
#pragma unroll
        for (int i = 0; i < 4; i++)
#pragma unroll
            for (int j = 0; j < 4; j++)
#pragma unroll
                for (int ks = 0; ks < 2; ks++)
                    acc[i][j] = __builtin_amdgcn_mfma_f32_16x16x32_bf16(
                        af[i][ks], bfr[j][ks], acc[i][j], 0, 0, 0);
        __syncthreads();               // drains vmcnt(0) (prefetch landed) + gates WAR
    }
#undef STAGE

    // epilogue: e[row] += sum_cols v[col] * tanh(C + bias[col] + qproj[b][col])
    const float* qp = mono ? qp_mono : qp_chunk;
    float* edst = mono ? e_mono : e_chunk;
    float vv[4], bb[4]; int nc[4];
#pragma unroll
    for (int j = 0; j < 4; j++){
        int ncol = (n0 - (mono ? 0 : 512)) + wn * 64 + j * 16 + l15;
        nc[j] = ncol;
        vv[j] = mono ? vnorm[ncol] : v_chunk[ncol];
        bb[j] = mono ? b_mono[ncol] : b_chunk[ncol];
    }
#pragma unroll
    for (int i = 0; i < 4; i++){
#pragma unroll
        for (int r = 0; r < 4; r++){
            int g = g0 + wm * 64 + i * 16 + quad * 4 + r;    // C/D: row = quad*4+reg
            int bidx = (u32)g / 4000u;
            float s = 0.f;
#pragma unroll
            for (int j = 0; j < 4; j++){
                float x2 = acc[i][j][r] + bb[j] + qp[bidx * 512 + nc[j]];
                s += vv[j] * tanh_fast(x2);
            }
            s += __shfl_xor(s, 1);
            s += __shfl_xor(s, 2);
            s += __shfl_xor(s, 4);
            s += __shfl_xor(s, 8);
            if (l15 == 0) atomicAdd(&edst[g], s);
        }
    }
}

// ---------------- fallback GEMM (small workspace): convert f32 key in-kernel ----------------
__global__ __launch_bounds__(256) void gemm_energy_f32(
    const float* __restrict__ key, const u16* __restrict__ Wt,
    const float* __restrict__ b_mono, const float* __restrict__ b_chunk,
    const float* __restrict__ vnorm, const float* __restrict__ v_chunk,
    const float* __restrict__ qp_mono, const float* __restrict__ qp_chunk,
    float* __restrict__ e_mono, float* __restrict__ e_chunk)
{
    __shared__ __align__(16) u16 As[128 * 40];
    __shared__ __align__(16) u16 Bs[128 * 40];
    const int tid = threadIdx.x;
    const int g0 = blockIdx.x * 128;
    const int nT = blockIdx.y;
    const bool mono = (nT < 4);
    const int n0 = nT * 128;
    const int lane = tid & 63;
    const int wave = tid >> 6;
    const int wm = wave >> 1, wn = wave & 1;
    const int l15 = lane & 15, quad = lane >> 4;

    f32x4 acc[4][4];
#pragma unroll
    for (int i = 0; i < 4; i++)
#pragma unroll
        for (int j = 0; j < 4; j++)
#pragma unroll
            for (int c = 0; c < 4; c++) acc[i][j][c] = 0.f;

    for (int k0 = 0; k0 < 512; k0 += 32){
        __syncthreads();
#pragma unroll
        for (int it = 0; it < 4; it++){
            int vid = tid + it * 256;
            int row = vid >> 3;
            int c4  = (vid & 7) << 2;
            float4 a = *reinterpret_cast<const float4*>(key + (size_t)(g0 + row) * 512 + k0 + c4);
            u32 p0 = (u32)f2bf(fmaxf(a.x, 0.f)) | ((u32)f2bf(fmaxf(a.y, 0.f)) << 16);
            u32 p1 = (u32)f2bf(fmaxf(a.z, 0.f)) | ((u32)f2bf(fmaxf(a.w, 0.f)) << 16);
            uint2 pk; pk.x = p0; pk.y = p1;
            *reinterpret_cast<uint2*>(&As[row * 40 + c4]) = pk;
        }
#pragma unroll
        for (int it = 0; it < 2; it++){
            int vid = tid + it * 256;
            int row = vid >> 2;
            int cb  = (vid & 3) << 3;
            uint4 b = *reinterpret_cast<const uint4*>(Wt + (size_t)(n0 + row) * 512 + k0 + cb);
            *reinterpret_cast<uint4*>(&Bs[row * 40 + cb]) = b;
        }
        __syncthreads();
        bf16x8 af[4], bfr[4];
#pragma unroll
        for (int i = 0; i < 4; i++){
            af[i]  = *reinterpret_cast<const bf16x8*>(&As[(wm * 64 + i * 16 + l15) * 40 + quad * 8]);
            bfr[i] = *reinterpret_cast<const bf16x8*>(&Bs[(wn * 64 + i * 16 + l15) * 40 + quad * 8]);
        }
#pragma unroll
        for (int i = 0; i < 4; i++)
#pragma unroll
            for (int j = 0; j < 4; j++)
                acc[i][j] = __builtin_amdgcn_mfma_f32_16x16x32_bf16(af[i], bfr[j], acc[i][j], 0, 0, 0);
    }

    const float* qp = mono ? qp_mono : qp_chunk;
    float* edst = mono ? e_mono : e_chunk;
    float vv[4], bb[4]; int nc[4];
#pragma unroll
    for (int j = 0; j < 4; j++){
        int ncol = (n0 - (mono ? 0 : 512)) + wn * 64 + j * 16 + l15;
        nc[j] = ncol;
        vv[j] = mono ? vnorm[ncol] : v_chunk[ncol];
        bb[j] = mono ? b_mono[ncol] : b_chunk[ncol];
    }
#pragma unroll
    for (int i = 0; i < 4; i++){
#pragma unroll
        for (int r = 0; r < 4; r++){
            int g = g0 + wm * 64 + i * 16 + quad * 4 + r;
            int bidx = (u32)g / 4000u;
            float s = 0.f;
#pragma unroll
            for (int j = 0; j < 4; j++){
                float x = acc[i][j][r] + bb[j] + qp[bidx * 512 + nc[j]];
                s += vv[j] * tanh_fast(x);
            }
            s += __shfl_xor(s, 1);
            s += __shfl_xor(s, 2);
            s += __shfl_xor(s, 4);
            s += __shfl_xor(s, 8);
            if (l15 == 0) atomicAdd(&edst[g], s);
        }
    }
}

// ---------------- per-batch scan: noise, p, alpha, chunk softmax, beta ----------------
#define IDX(t) ((t) + ((t) >> 4))

__global__ __launch_bounds__(512) void scan_energy(
    const float* __restrict__ e_mono, const float* __restrict__ e_chunk,
    const int* __restrict__ mask, const float* __restrict__ r_mono,
    float* __restrict__ out_alpha, float* __restrict__ beta)
{
    __shared__ float P[4256];
    __shared__ float AL[4256];
    __shared__ float SE[4256];
    __shared__ float red[512];
    const int b = blockIdx.x;
    const int tid = threadIdx.x;
    const float r = r_mono[0];
    const int t0 = tid * 8;

    float l[8];
    float lsum = 0.f;
#pragma unroll
    for (int i = 0; i < 8; i++){
        int t = t0 + i;
        if (t < T_LEN){
            int fl = b * T_LEN + t;
            float e = e_mono[fl] + r;
            if (mask[fl] == 0) e = NEG_INF;
            float x = e + jax_noise((u32)fl);
            float p = 1.0f / (1.0f + expf(-x));
            P[IDX(t)] = p;
            float om = 1.0f - p;
            om = fminf(fmaxf(om, 1e-6f), 1.0f);
            l[i] = logf(om);
            lsum += l[i];
        } else l[i] = 0.f;
    }
    red[tid] = lsum;
    __syncthreads();
#pragma unroll
    for (int off = 1; off < 512; off <<= 1){
        float v = (tid >= off) ? red[tid - off] : 0.f;
        __syncthreads();
        red[tid] += v;
        __syncthreads();
    }
    float run = red[tid] - lsum;
#pragma unroll
    for (int i = 0; i < 8; i++){
        int t = t0 + i;
        if (t < T_LEN){
            float alpha = P[IDX(t)] * expf(run);
            run += l[i];
            AL[IDX(t)] = alpha;
            out_alpha[b * T_LEN + t] = alpha;
        }
    }

    float ec[8]; float lmax = NEG_INF;
#pragma unroll
    for (int i = 0; i < 8; i++){
        int t = t0 + i;
        if (t < T_LEN){
            int fl = b * T_LEN + t;
            float e = e_chunk[fl];
            if (mask[fl] == 0) e = NEG_INF;
            ec[i] = e;
            lmax = fmaxf(lmax, e);
        } else ec[i] = NEG_INF;
    }
    __syncthreads();
    red[tid] = lmax;
    __syncthreads();
    for (int off = 256; off >= 1; off >>= 1){
        if (tid < off) red[tid] = fmaxf(red[tid], red[tid + off]);
        __syncthreads();
    }
    float m = red[0];
#pragma unroll
    for (int i = 0; i < 8; i++){
        int t = t0 + i;
        if (t < T_LEN) SE[IDX(t)] = fmaxf(expf(ec[i] - m), 1e-5f);
    }
    __syncthreads();
#pragma unroll
    for (int i = 0; i < 8; i++){
        int t = t0 + i;
        if (t < T_LEN){
            float d = 0.f;
            int lo = t - 7; if (lo < 0) lo = 0;
            for (int s = lo; s <= t; s++) d += SE[IDX(s)];
            P[IDX(t)] = AL[IDX(t)] / d;
        }
    }
    __syncthreads();
#pragma unroll
    for (int i = 0; i < 8; i++){
        int t = t0 + i;
        if (t < T_LEN){
            float s2 = 0.f;
            int hi = t + 7; if (hi > T_LEN - 1) hi = T_LEN - 1;
            for (int s = t; s <= hi; s++) s2 += P[IDX(s)];
            beta[b * T_LEN + t] = SE[IDX(t)] * s2;
        }
    }
}

// ---------------- cv = sum_t beta[t] * value[t,:] (into d_out directly) ----------------
// 512 blocks (16 b x 32 chunks of 125 rows): 2 blocks/CU for the 131 MB stream.
__global__ __launch_bounds__(256) void cv_accum(const float* __restrict__ value,
                                                const float* __restrict__ beta,
                                                float* __restrict__ outcv){
    const int b = blockIdx.x >> 5;
    const int c = blockIdx.x & 31;
    const int tid = threadIdx.x;
    __shared__ float bsh[125];
    __shared__ float part[512];
    int tstart = c * 125;
    if (tid < 125) bsh[tid] = beta[b * T_LEN + tstart + tid];
    __syncthreads();
    int dl = (tid & 127) * 4;
    int trow = tid >> 7;
    float4 a = {0.f, 0.f, 0.f, 0.f};
    for (int t = trow; t < 125; t += 2){
        float bt = bsh[t];
        float4 v = *reinterpret_cast<const float4*>(
            value + (size_t)(b * T_LEN + tstart + t) * 512 + dl);
        a.x += bt * v.x; a.y += bt * v.y; a.z += bt * v.z; a.w += bt * v.w;
    }
    // pair-reduce trow 0/1 in LDS: halves same-address atomic traffic
    if (trow == 1){
        part[(tid & 127) * 4 + 0] = a.x;
        part[(tid & 127) * 4 + 1] = a.y;
        part[(tid & 127) * 4 + 2] = a.z;
        part[(tid & 127) * 4 + 3] = a.w;
    }
    __syncthreads();
    if (trow == 0){
        a.x += part[(tid & 127) * 4 + 0];
        a.y += part[(tid & 127) * 4 + 1];
        a.z += part[(tid & 127) * 4 + 2];
        a.w += part[(tid & 127) * 4 + 3];
        atomicAdd(&outcv[b * 512 + dl + 0], a.x);
        atomicAdd(&outcv[b * 512 + dl + 1], a.y);
        atomicAdd(&outcv[b * 512 + dl + 2], a.z);
        atomicAdd(&outcv[b * 512 + dl + 3], a.w);
    }
}

// ---------------- launch ----------------
extern "C" void kernel_launch(void* const* d_in, const int* in_sizes, int n_in,
                              void* d_out, int out_size, void* d_ws, size_t ws_size,
                              hipStream_t stream)
{
    const float* key      = (const float*)d_in[0];
    const float* value    = (const float*)d_in[1];
    const float* query    = (const float*)d_in[2];
    const int*   mask     = (const int*)d_in[3];
    const float* wk_mono  = (const float*)d_in[4];
    const float* bk_mono  = (const float*)d_in[5];
    const float* wq_mono  = (const float*)d_in[6];
    const float* v_mono   = (const float*)d_in[7];
    const float* g_mono   = (const float*)d_in[8];
    const float* r_mono   = (const float*)d_in[9];
    const float* wk_chunk = (const float*)d_in[10];
    const float* bk_chunk = (const float*)d_in[11];
    const float* wq_chunk = (const float*)d_in[12];
    const float* v_chunk  = (const float*)d_in[13];

    float* ws      = (float*)d_ws;
    float* e_mono  = ws;                 // 64000
    float* e_chunk = ws + 64000;         // 64000
    float* beta    = ws + 136192;        // 64000
    float* qp_mono = ws + 200192;        // 8192
    float* qp_chunk= ws + 208384;        // 8192
    float* vnorm   = ws + 216576;        // 512
    u16*   Wt      = (u16*)(ws + 217088);// 1024x512 bf16 (1 MB)
    u16*   kb      = (u16*)(ws + 479232);// 64000x512 bf16 (65.5 MB) if it fits

    const size_t NEED = 479232u * 4u + (size_t)64000 * 512 * 2;
    const bool big = ws_size >= NEED;

    prep_combined<<<big ? 8612 : 612, 512, 0, stream>>>(
        v_mono, g_mono, query, wq_mono, wq_chunk, wk_mono, wk_chunk, key,
        vnorm, qp_mono, qp_chunk, Wt, kb, e_mono, (float*)d_out);

    if (big){
        gemm_energy_pre<<<4096, 256, 0, stream>>>(kb, Wt, bk_mono, bk_chunk,
                                                  vnorm, v_chunk, qp_mono, qp_chunk,
                                                  e_mono, e_chunk);
    } else {
        gemm_energy_f32<<<dim3(500, 8), 256, 0, stream>>>(key, Wt, bk_mono, bk_chunk,
                                                          vnorm, v_chunk, qp_mono, qp_chunk,
                                                          e_mono, e_chunk);
    }
    scan_energy<<<16, 512, 0, stream>>>(e_mono, e_chunk, mask, r_mono,
                                        (float*)d_out + 8192, beta);
    cv_accum<<<512, 256, 0, stream>>>(value, beta, (float*)d_out);
}

// Round 6
// 431.192 us; speedup vs baseline: 1.2352x; 1.0528x over previous
//
#include <hip/hip_runtime.h>
#include <stdint.h>

typedef unsigned short u16;
typedef unsigned int   u32;

#define T_LEN 4000
#define NEG_INF (-3.4028234663852886e38f)

typedef __bf16 bf16x8 __attribute__((ext_vector_type(8)));
typedef float  f32x4  __attribute__((ext_vector_type(4)));

__device__ __forceinline__ u16 f2bf(float f){
    union { float f; u32 i; } v; v.f = f;
    u32 u = v.i;
    u32 r = (u + 0x7FFFu + ((u >> 16) & 1u)) >> 16;
    return (u16)r;
}
__device__ __forceinline__ float tanh_fast(float x){
    float ax = fabsf(x);
    float a = __expf(-2.0f * ax);
    float t = (1.0f - a) / (1.0f + a);
    return copysignf(t, x);
}
__device__ __forceinline__ u32 rotl32(u32 x, int n){ return (x << n) | (x >> (32 - n)); }

// async global->LDS, 16B per lane (global_load_lds_dwordx4).
// LDS dest must be linear in lane order: base + lane*16.
__device__ __forceinline__ void gll16(const void* g, void* l){
    __builtin_amdgcn_global_load_lds(
        (__attribute__((address_space(1))) void*)g,
        (__attribute__((address_space(3))) void*)l, 16, 0, 0);
}

// jax.random.normal(jax.random.key(123), (16,4000), f32) — threefry2x32. [verified]
__device__ float jax_noise(u32 idx){
    const u32 k0 = 0u, k1 = 123u;
    const u32 k2 = k0 ^ k1 ^ 0x1BD11BDAu;
    u32 x0 = k0;
    u32 x1 = idx + k1;
#define RND(r) { x0 += x1; x1 = rotl32(x1, r); x1 ^= x0; }
    RND(13) RND(15) RND(26) RND(6)   x0 += k1; x1 += k2 + 1u;
    RND(17) RND(29) RND(16) RND(24)  x0 += k2; x1 += k0 + 2u;
    RND(13) RND(15) RND(26) RND(6)   x0 += k0; x1 += k1 + 3u;
    RND(17) RND(29) RND(16) RND(24)  x0 += k1; x1 += k2 + 4u;
    RND(13) RND(15) RND(26) RND(6)   x0 += k2; x1 += k0 + 5u;
#undef RND
    u32 bits = x0 ^ x1;
    union { u32 i; float f; } u;
    u.i = (bits >> 9) | 0x3F800000u;
    float f01 = u.f - 1.0f;
    const float minval = -0.99999994f;
    float uu = f01 * (1.0f - minval) + minval;
    uu = fmaxf(uu, minval);
    return 1.41421356f * erfinvf(uu);
}

// ---------------- merged prep: vnorm, qproj, W transpose, zeroing, key->bf16 ----------------
__global__ __launch_bounds__(512) void prep_combined(
    const float* __restrict__ v_mono, const float* __restrict__ g_mono,
    const float* __restrict__ query, const float* __restrict__ wq_mono,
    const float* __restrict__ wq_chunk,
    const float* __restrict__ wk_mono, const float* __restrict__ wk_chunk,
    const float* __restrict__ key,
    float* __restrict__ vn, float* __restrict__ qp_mono, float* __restrict__ qp_chunk,
    u16* __restrict__ Wt, u16* __restrict__ kb,
    float* __restrict__ ezero, float* __restrict__ outcv)
{
    __shared__ float shf[512];
    __shared__ u16 tile[32][33];
    const int blk = blockIdx.x;
    const int tid = threadIdx.x;
    if (blk == 0){
        float v = v_mono[tid];
        shf[tid] = v * v;
        __syncthreads();
        for (int off = 256; off >= 1; off >>= 1){
            if (tid < off) shf[tid] += shf[tid + off];
            __syncthreads();
        }
        float g = g_mono[0];
        vn[tid] = g * v / sqrtf(shf[0]);
    } else if (blk <= 32){
        int b = (blk - 1) >> 1;
        int which = (blk - 1) & 1;
        const float* W = which ? wq_chunk : wq_mono;
        float* out = which ? qp_chunk : qp_mono;
        shf[tid] = query[b * 512 + tid];
        __syncthreads();
        float acc = 0.f;
        for (int k = 0; k < 512; k++) acc += shf[k] * W[k * 512 + tid];
        out[b * 512 + tid] = acc;
    } else if (blk <= 544){
        int idx = blk - 33;                     // 0..511
        int kt = (idx & 15) * 32, nt = (idx >> 4) * 32;
        int c = tid & 31, r = tid >> 5;         // 32 cols x 16 rows
        const float* src = (nt < 512) ? wk_mono : wk_chunk;
        int nbase = (nt < 512) ? nt : nt - 512;
#pragma unroll
        for (int i = 0; i < 2; i++){
            int kk = r + i * 16;
            tile[kk][c] = f2bf(src[(size_t)(kt + kk) * 512 + nbase + c]);
        }
        __syncthreads();
#pragma unroll
        for (int i = 0; i < 2; i++){
            int nn = r + i * 16;
            Wt[(size_t)(nt + nn) * 512 + kt + c] = tile[c][nn];
        }
    } else if (blk < 608){
        int i = ((blk - 545) * 512 + tid) * 4;   // zero e_mono|e_chunk (128000 floats)
        if (i < 128000){
            float4 z = {0.f, 0.f, 0.f, 0.f};
            *reinterpret_cast<float4*>(ezero + i) = z;
        }
    } else if (blk < 612){
        int i = ((blk - 608) * 512 + tid) * 4;   // zero cv accum target (8192 floats)
        float4 z = {0.f, 0.f, 0.f, 0.f};
        *reinterpret_cast<float4*>(outcv + i) = z;
    } else {
        size_t i = ((size_t)(blk - 612) * 512 + tid) * 8;
        float4 a = *reinterpret_cast<const float4*>(key + i);
        float4 b = *reinterpret_cast<const float4*>(key + i + 4);
        uint4 pk;
        pk.x = (u32)f2bf(fmaxf(a.x, 0.f)) | ((u32)f2bf(fmaxf(a.y, 0.f)) << 16);
        pk.y = (u32)f2bf(fmaxf(a.z, 0.f)) | ((u32)f2bf(fmaxf(a.w, 0.f)) << 16);
        pk.z = (u32)f2bf(fmaxf(b.x, 0.f)) | ((u32)f2bf(fmaxf(b.y, 0.f)) << 16);
        pk.w = (u32)f2bf(fmaxf(b.z, 0.f)) | ((u32)f2bf(fmaxf(b.w, 0.f)) << 16);
        *reinterpret_cast<uint4*>(kb + i) = pk;
    }
}

// ---------------- main GEMM + energy epilogue ----------------
// 256x256 tile, 16 waves (4M x 4N, 64x64 each), BK=64, double-buffered.
// Halves total staged traffic vs 128x128 (1.02 GB -> 512 MB) and doubles
// FLOP/staged-byte. gll16 staging, XOR swizzle both sides (verified 0-conflict).
// In-block LDS row-reduce -> one coalesced atomic per row per block.
__global__ __launch_bounds__(1024) void gemm_energy_pre(
    const u16* __restrict__ kb, const u16* __restrict__ Wt,
    const float* __restrict__ b_mono, const float* __restrict__ b_chunk,
    const float* __restrict__ vnorm, const float* __restrict__ v_chunk,
    const float* __restrict__ qp_mono, const float* __restrict__ qp_chunk,
    float* __restrict__ e_mono, float* __restrict__ e_chunk)
{
    __shared__ __align__(16) u16 As[2][256 * 64];   // 2 x 32 KiB
    __shared__ __align__(16) u16 Bs[2][256 * 64];   // 2 x 32 KiB  (128 KiB total)
    __shared__ float part[4][256];                  // per-wn row partials (4 KiB)

    const int bid = blockIdx.x;
    const int swz = (bid & 7) * 125 + (bid >> 3);   // bijective (1000 % 8 == 0)
    const int xt = swz >> 2;                        // 0..249 (256-row tile)
    const int nT = swz & 3;                         // 0..3   (256-col tile)
    const int g0 = xt * 256;
    const int n0 = nT * 256;
    const bool mono = (nT < 2);

    const int tid = threadIdx.x;
    const int lane = tid & 63;
    const int wave = tid >> 6;                      // 0..15
    const int wm = wave >> 2, wn = wave & 3;        // 4M x 4N waves
    const int l15 = lane & 15, quad = lane >> 4;

    f32x4 acc[4][4];
#pragma unroll
    for (int i = 0; i < 4; i++)
#pragma unroll
        for (int j = 0; j < 4; j++)
#pragma unroll
            for (int c = 0; c < 4; c++) acc[i][j][c] = 0.f;

    const u16* aG = kb + (size_t)g0 * 512;
    const u16* bG = Wt + (size_t)n0 * 512;

    // stage one BK=64 tile (A 256x64 + B 256x64) into buffer bsel.
    // 2048 x 16B slots per matrix, 2 per thread; global source pre-swizzled.
#define STAGE(bsel, k0) do{                                                     \
    _Pragma("unroll") for (int it_ = 0; it_ < 2; it_++){                        \
        int vid = tid + it_ * 1024;                                             \
        int row = vid >> 3;                                                     \
        int sl  = (vid & 7) ^ (row & 7);                                        \
        gll16(aG + (size_t)row * 512 + (k0) + sl * 8, &As[bsel][vid * 8]);      \
        gll16(bG + (size_t)row * 512 + (k0) + sl * 8, &Bs[bsel][vid * 8]);      \
    }                                                                           \
}while(0)

    STAGE(0, 0);
    __syncthreads();                   // tile 0 resident

#pragma unroll 1
    for (int kt = 0; kt < 8; kt++){
        const int cur = kt & 1;
        if (kt < 7) STAGE(cur ^ 1, (kt + 1) * 64);   // prefetch next tile
#pragma unroll
        for (int ks = 0; ks < 2; ks++){
            bf16x8 af[4], bf[4];
#pragma unroll
            for (int i = 0; i < 4; i++){
                int ra = wm * 64 + i * 16 + l15;
                af[i] = *reinterpret_cast<const bf16x8*>(
                    &As[cur][ra * 64 + (((ks * 4 + quad) ^ (ra & 7)) << 3)]);
            }
#pragma unroll
            for (int j = 0; j < 4; j++){
                int rb = wn * 64 + j * 16 + l15;
                bf[j] = *reinterpret_cast<const bf16x8*>(
                    &Bs[cur][rb * 64 + (((ks * 4 + quad) ^ (rb & 7)) << 3)]);
            }
#pragma unroll
            for (int i = 0; i < 4; i++)
#pragma unroll
                for (int j = 0; j < 4; j++)
                    acc[i][j] = __builtin_amdgcn_mfma_f32_16x16x32_bf16(
                        af[i], bf[j], acc[i][j], 0, 0, 0);
        }
        __syncthreads();               // prefetch landed + WAR gate
    }
#undef STAGE

    // ---- epilogue: e[row] += sum_cols v[col] * tanh(C + bias + qproj) ----
    const float* qp = mono ? qp_mono : qp_chunk;
    float* edst = mono ? e_mono : e_chunk;
    const int b0 = g0 / 4000;
    const int b1 = (g0 + 255) / 4000;
    float vv[4], bb[4], qA[4], qB[4];
#pragma unroll
    for (int j = 0; j < 4; j++){
        int c = (n0 - (mono ? 0 : 512)) + wn * 64 + j * 16 + l15;
        vv[j] = mono ? vnorm[c] : v_chunk[c];
        bb[j] = mono ? b_mono[c] : b_chunk[c];
        qA[j] = qp[b0 * 512 + c];
        qB[j] = qp[b1 * 512 + c];
    }
#pragma unroll
    for (int i = 0; i < 4; i++){
#pragma unroll
        for (int r = 0; r < 4; r++){
            int rl = wm * 64 + i * 16 + quad * 4 + r;        // local row
            int bidx = (u32)(g0 + rl) / 4000u;
            float s = 0.f;
#pragma unroll
            for (int j = 0; j < 4; j++){
                float x = acc[i][j][r] + bb[j] + (bidx == b0 ? qA[j] : qB[j]);
                s += vv[j] * tanh_fast(x);
            }
            s += __shfl_xor(s, 1);
            s += __shfl_xor(s, 2);
            s += __shfl_xor(s, 4);
            s += __shfl_xor(s, 8);
            if (l15 == 0) part[wn][rl] = s;                  // unique (wn, rl)
        }
    }
    __syncthreads();
    if ((wave & 3) == 0){                                    // 4 waves, one per wm
        int rl = wm * 64 + lane;
        float t = part[0][rl] + part[1][rl] + part[2][rl] + part[3][rl];
        atomicAdd(&edst[g0 + rl], t);                        // 2 atomics/row total
    }
}

// ---------------- fallback GEMM (small workspace): convert f32 key in-kernel ----------------
__global__ __launch_bounds__(256) void gemm_energy_f32(
    const float* __restrict__ key, const u16* __restrict__ Wt,
    const float* __restrict__ b_mono, const float* __restrict__ b_chunk,
    const float* __restrict__ vnorm, const float* __restrict__ v_chunk,
    const float* __restrict__ qp_mono, const float* __restrict__ qp_chunk,
    float* __restrict__ e_mono, float* __restrict__ e_chunk)
{
    __shared__ __align__(16) u16 As[128 * 40];
    __shared__ __align__(16) u16 Bs[128 * 40];
    const int tid = threadIdx.x;
    const int g0 = blockIdx.x * 128;
    const int nT = blockIdx.y;
    const bool mono = (nT < 4);
    const int n0 = nT * 128;
    const int lane = tid & 63;
    const int wave = tid >> 6;
    const int wm = wave >> 1, wn = wave & 1;
    const int l15 = lane & 15, quad = lane >> 4;

    f32x4 acc[4][4];
#pragma unroll
    for (int i = 0; i < 4; i++)
#pragma unroll
        for (int j = 0; j < 4; j++)
#pragma unroll
            for (int c = 0; c < 4; c++) acc[i][j][c] = 0.f;

    for (int k0 = 0; k0 < 512; k0 += 32){
        __syncthreads();
#pragma unroll
        for (int it = 0; it < 4; it++){
            int vid = tid + it * 256;
            int row = vid >> 3;
            int c4  = (vid & 7) << 2;
            float4 a = *reinterpret_cast<const float4*>(key + (size_t)(g0 + row) * 512 + k0 + c4);
            u32 p0 = (u32)f2bf(fmaxf(a.x, 0.f)) | ((u32)f2bf(fmaxf(a.y, 0.f)) << 16);
            u32 p1 = (u32)f2bf(fmaxf(a.z, 0.f)) | ((u32)f2bf(fmaxf(a.w, 0.f)) << 16);
            uint2 pk; pk.x = p0; pk.y = p1;
            *reinterpret_cast<uint2*>(&As[row * 40 + c4]) = pk;
        }
#pragma unroll
        for (int it = 0; it < 2; it++){
            int vid = tid + it * 256;
            int row = vid >> 2;
            int cb  = (vid & 3) << 3;
            uint4 b = *reinterpret_cast<const uint4*>(Wt + (size_t)(n0 + row) * 512 + k0 + cb);
            *reinterpret_cast<uint4*>(&Bs[row * 40 + cb]) = b;
        }
        __syncthreads();
        bf16x8 af[4], bfr[4];
#pragma unroll
        for (int i = 0; i < 4; i++){
            af[i]  = *reinterpret_cast<const bf16x8*>(&As[(wm * 64 + i * 16 + l15) * 40 + quad * 8]);
            bfr[i] = *reinterpret_cast<const bf16x8*>(&Bs[(wn * 64 + i * 16 + l15) * 40 + quad * 8]);
        }
#pragma unroll
        for (int i = 0; i < 4; i++)
#pragma unroll
            for (int j = 0; j < 4; j++)
                acc[i][j] = __builtin_amdgcn_mfma_f32_16x16x32_bf16(af[i], bfr[j], acc[i][j], 0, 0, 0);
    }

    const float* qp = mono ? qp_mono : qp_chunk;
    float* edst = mono ? e_mono : e_chunk;
    float vv[4], bb[4]; int nc[4];
#pragma unroll
    for (int j = 0; j < 4; j++){
        int ncol = (n0 - (mono ? 0 : 512)) + wn * 64 + j * 16 + l15;
        nc[j] = ncol;
        vv[j] = mono ? vnorm[ncol] : v_chunk[ncol];
        bb[j] = mono ? b_mono[ncol] : b_chunk[ncol];
    }
#pragma unroll
    for (int i = 0; i < 4; i++){
#pragma unroll
        for (int r = 0; r < 4; r++){
            int g = g0 + wm * 64 + i * 16 + quad * 4 + r;
            int bidx = (u32)g / 4000u;
            float s = 0.f;
#pragma unroll
            for (int j = 0; j < 4; j++){
                float x = acc[i][j][r] + bb[j] + qp[bidx * 512 + nc[j]];
                s += vv[j] * tanh_fast(x);
            }
            s += __shfl_xor(s, 1);
            s += __shfl_xor(s, 2);
            s += __shfl_xor(s, 4);
            s += __shfl_xor(s, 8);
            if (l15 == 0) atomicAdd(&edst[g], s);
        }
    }
}

// ---------------- per-batch scan: noise, p, alpha, chunk softmax, beta ----------------
#define IDX(t) ((t) + ((t) >> 4))

__global__ __launch_bounds__(512) void scan_energy(
    const float* __restrict__ e_mono, const float* __restrict__ e_chunk,
    const int* __restrict__ mask, const float* __restrict__ r_mono,
    float* __restrict__ out_alpha, float* __restrict__ beta)
{
    __shared__ float P[4256];
    __shared__ float AL[4256];
    __shared__ float SE[4256];
    __shared__ float red[512];
    const int b = blockIdx.x;
    const int tid = threadIdx.x;
    const float r = r_mono[0];
    const int t0 = tid * 8;

    float l[8];
    float lsum = 0.f;
#pragma unroll
    for (int i = 0; i < 8; i++){
        int t = t0 + i;
        if (t < T_LEN){
            int fl = b * T_LEN + t;
            float e = e_mono[fl] + r;
            if (mask[fl] == 0) e = NEG_INF;
            float x = e + jax_noise((u32)fl);
            float p = 1.0f / (1.0f + expf(-x));
            P[IDX(t)] = p;
            float om = 1.0f - p;
            om = fminf(fmaxf(om, 1e-6f), 1.0f);
            l[i] = logf(om);
            lsum += l[i];
        } else l[i] = 0.f;
    }
    red[tid] = lsum;
    __syncthreads();
#pragma unroll
    for (int off = 1; off < 512; off <<= 1){
        float v = (tid >= off) ? red[tid - off] : 0.f;
        __syncthreads();
        red[tid] += v;
        __syncthreads();
    }
    float run = red[tid] - lsum;
#pragma unroll
    for (int i = 0; i < 8; i++){
        int t = t0 + i;
        if (t < T_LEN){
            float alpha = P[IDX(t)] * expf(run);
            run += l[i];
            AL[IDX(t)] = alpha;
            out_alpha[b * T_LEN + t] = alpha;
        }
    }

    float ec[8]; float lmax = NEG_INF;
#pragma unroll
    for (int i = 0; i < 8; i++){
        int t = t0 + i;
        if (t < T_LEN){
            int fl = b * T_LEN + t;
            float e = e_chunk[fl];
            if (mask[fl] == 0) e = NEG_INF;
            ec[i] = e;
            lmax = fmaxf(lmax, e);
        } else ec[i] = NEG_INF;
    }
    __syncthreads();
    red[tid] = lmax;
    __syncthreads();
    for (int off = 256; off >= 1; off >>= 1){
        if (tid < off) red[tid] = fmaxf(red[tid], red[tid + off]);
        __syncthreads();
    }
    float m = red[0];
#pragma unroll
    for (int i = 0; i < 8; i++){
        int t = t0 + i;
        if (t < T_LEN) SE[IDX(t)] = fmaxf(expf(ec[i] - m), 1e-5f);
    }
    __syncthreads();
#pragma unroll
    for (int i = 0; i < 8; i++){
        int t = t0 + i;
        if (t < T_LEN){
            float d = 0.f;
            int lo = t - 7; if (lo < 0) lo = 0;
            for (int s = lo; s <= t; s++) d += SE[IDX(s)];
            P[IDX(t)] = AL[IDX(t)] / d;
        }
    }
    __syncthreads();
#pragma unroll
    for (int i = 0; i < 8; i++){
        int t = t0 + i;
        if (t < T_LEN){
            float s2 = 0.f;
            int hi = t + 7; if (hi > T_LEN - 1) hi = T_LEN - 1;
            for (int s = t; s <= hi; s++) s2 += P[IDX(s)];
            beta[b * T_LEN + t] = SE[IDX(t)] * s2;
        }
    }
}

// ---------------- cv = sum_t beta[t] * value[t,:] (into d_out directly) ----------------
// 512 blocks (16 b x 32 chunks of 125 rows): 2 blocks/CU for the 131 MB stream.
__global__ __launch_bounds__(256) void cv_accum(const float* __restrict__ value,
                                                const float* __restrict__ beta,
                                                float* __restrict__ outcv){
    const int b = blockIdx.x >> 5;
    const int c = blockIdx.x & 31;
    const int tid = threadIdx.x;
    __shared__ float bsh[125];
    __shared__ float part[512];
    int tstart = c * 125;
    if (tid < 125) bsh[tid] = beta[b * T_LEN + tstart + tid];
    __syncthreads();
    int dl = (tid & 127) * 4;
    int trow = tid >> 7;
    float4 a = {0.f, 0.f, 0.f, 0.f};
    for (int t = trow; t < 125; t += 2){
        float bt = bsh[t];
        float4 v = *reinterpret_cast<const float4*>(
            value + (size_t)(b * T_LEN + tstart + t) * 512 + dl);
        a.x += bt * v.x; a.y += bt * v.y; a.z += bt * v.z; a.w += bt * v.w;
    }
    if (trow == 1){
        part[(tid & 127) * 4 + 0] = a.x;
        part[(tid & 127) * 4 + 1] = a.y;
        part[(tid & 127) * 4 + 2] = a.z;
        part[(tid & 127) * 4 + 3] = a.w;
    }
    __syncthreads();
    if (trow == 0){
        a.x += part[(tid & 127) * 4 + 0];
        a.y += part[(tid & 127) * 4 + 1];
        a.z += part[(tid & 127) * 4 + 2];
        a.w += part[(tid & 127) * 4 + 3];
        atomicAdd(&outcv[b * 512 + dl + 0], a.x);
        atomicAdd(&outcv[b * 512 + dl + 1], a.y);
        atomicAdd(&outcv[b * 512 + dl + 2], a.z);
        atomicAdd(&outcv[b * 512 + dl + 3], a.w);
    }
}

// ---------------- launch ----------------
extern "C" void kernel_launch(void* const* d_in, const int* in_sizes, int n_in,
                              void* d_out, int out_size, void* d_ws, size_t ws_size,
                              hipStream_t stream)
{
    const float* key      = (const float*)d_in[0];
    const float* value    = (const float*)d_in[1];
    const float* query    = (const float*)d_in[2];
    const int*   mask     = (const int*)d_in[3];
    const float* wk_mono  = (const float*)d_in[4];
    const float* bk_mono  = (const float*)d_in[5];
    const float* wq_mono  = (const float*)d_in[6];
    const float* v_mono   = (const float*)d_in[7];
    const float* g_mono   = (const float*)d_in[8];
    const float* r_mono   = (const float*)d_in[9];
    const float* wk_chunk = (const float*)d_in[10];
    const float* bk_chunk = (const float*)d_in[11];
    const float* wq_chunk = (const float*)d_in[12];
    const float* v_chunk  = (const float*)d_in[13];

    float* ws      = (float*)d_ws;
    float* e_mono  = ws;                 // 64000
    float* e_chunk = ws + 64000;         // 64000
    float* beta    = ws + 136192;        // 64000
    float* qp_mono = ws + 200192;        // 8192
    float* qp_chunk= ws + 208384;        // 8192
    float* vnorm   = ws + 216576;        // 512
    u16*   Wt      = (u16*)(ws + 217088);// 1024x512 bf16 (1 MB)
    u16*   kb      = (u16*)(ws + 479232);// 64000x512 bf16 (65.5 MB) if it fits

    const size_t NEED = 479232u * 4u + (size_t)64000 * 512 * 2;
    const bool big = ws_size >= NEED;

    prep_combined<<<big ? 8612 : 612, 512, 0, stream>>>(
        v_mono, g_mono, query, wq_mono, wq_chunk, wk_mono, wk_chunk, key,
        vnorm, qp_mono, qp_chunk, Wt, kb, e_mono, (float*)d_out);

    if (big){
        gemm_energy_pre<<<1000, 1024, 0, stream>>>(kb, Wt, bk_mono, bk_chunk,
                                                   vnorm, v_chunk, qp_mono, qp_chunk,
                                                   e_mono, e_chunk);
    } else {
        gemm_energy_f32<<<dim3(500, 8), 256, 0, stream>>>(key, Wt, bk_mono, bk_chunk,
                                                          vnorm, v_chunk, qp_mono, qp_chunk,
                                                          e_mono, e_chunk);
    }
    scan_energy<<<16, 512, 0, stream>>>(e_mono, e_chunk, mask, r_mono,
                                        (float*)d_out + 8192, beta);
    cv_accum<<<512, 256, 0, stream>>>(value, beta, (float*)d_out);
}